// Round 1
// baseline (367.657 us; speedup 1.0000x reference)
//
#include <hip/hip_runtime.h>
#include <hip/hip_bf16.h>
#include <hip/hip_cooperative_groups.h>
#include <math.h>

namespace cg = cooperative_groups;

#define LTOT 36864      // 192*192
#define NH 4
#define NCHUNK 256
#define CHU 144
#define NBUCK 128
#define NSEG 144        // 36864 / 256
#define HW_ 192
#define VTS 148         // VT row stride (u16)

typedef unsigned int u32;
typedef unsigned short u16;
typedef unsigned long long u64;
typedef __attribute__((ext_vector_type(4))) short short4v;
typedef __attribute__((ext_vector_type(4))) float f32x4;

__device__ __forceinline__ u32 pkbf(float a, float b){
  union { __hip_bfloat162 h2; u32 u; } cv;
  cv.h2 = __float22bfloat162_rn(float2{a,b});
  return cv.u;
}
__device__ __forceinline__ float bflo(u32 w){ return __uint_as_float(w<<16); }
__device__ __forceinline__ float bfhi(u32 w){ return __uint_as_float(w & 0xffff0000u); }

// Shared-memory union: one allocation reused by all phases (max = attn: 38784 B)
union __align__(16) SMu {
  struct { float xs[32*108]; float xq[64*8]; } c;                       // 15872 B
  struct { u16 Klds[432*8]; u16 Qlds[CHU*8]; u16 VT[3][32*VTS];
           float qn[CHU]; int spos_l[CHU]; } a;                          // 38784 B
  struct { int pre2[2][NBUCK]; int tot2[2][NBUCK]; int scv[NBUCK];
           int segbase[NBUCK]; int wh[4][NBUCK]; } s;                    // 5120 B
};

// ---------------- phase 0: zero hist ----------------
__device__ __forceinline__ void phase_zero(int gid, int gsize, int* __restrict__ hist){
  for (int i = gid; i < NH*NSEG*NBUCK; i += gsize) hist[i] = 0;
}

// ---------------- phase 1: conv + hash + hist + bf16 K/Q/V pack (unsorted) ----------------
// 576 units; 320-thread blocks (wave 4 helps stage, idles in compute).
__device__ __forceinline__ void phase_conv(const float* __restrict__ x,
    const float* __restrict__ wm, const float* __restrict__ bm,
    const float* __restrict__ wa, const float* __restrict__ ba,
    const float* __restrict__ rot,
    u16* __restrict__ Ku, u16* __restrict__ Qu, u16* __restrict__ Vu,
    int* __restrict__ code, int* __restrict__ hist,
    int id, int t, SMu& sm)
{
  float* xs = sm.c.xs;
  float* xq = sm.c.xq;
  const int bx = id % 12, by = id / 12;

  for (int idx=t; idx<3456; idx+=320){
    int ci = idx/108, rem = idx-ci*108;
    int iy = rem/18,  ix = rem-iy*18;
    int yy = by*4+iy-1, xx = bx*16+ix-1;
    float v = 0.f;
    if (yy>=0 && yy<HW_ && xx>=0 && xx<HW_) v = x[ci*LTOT + yy*HW_ + xx];
    xs[idx] = v;
  }
  __syncthreads();
  const int lane = t & 63;
  if (t < 256){
    const int w  = __builtin_amdgcn_readfirstlane(t>>6);
    const int co0 = 2*w, cb = 8*w;
    const int ix = lane & 15, iy = lane >> 4;
    float a0 = bm[co0], a1 = bm[co0+1];
    float acc[8];
    #pragma unroll
    for (int co=0;co<8;co++) acc[co] = ba[cb+co];
    const float* xb  = xs + iy*18 + ix;
    const float* w0p = wm + co0*288;
    const float* w1p = w0p + 288;
    for (int ci=0; ci<32; ci++){
      const float* xp = xb + ci*108;
      float x00=xp[0],  x01=xp[1],  x02=xp[2];
      float x10=xp[18], x11=xp[19], x12=xp[20];
      float x20=xp[36], x21=xp[37], x22=xp[38];
      const float* w0 = w0p + ci*9;
      const float* w1 = w1p + ci*9;
      a0 += x00*w0[0]+x01*w0[1]+x02*w0[2]
          + x10*w0[3]+x11*w0[4]+x12*w0[5]
          + x20*w0[6]+x21*w0[7]+x22*w0[8];
      a1 += x00*w1[0]+x01*w1[1]+x02*w1[2]
          + x10*w1[3]+x11*w1[4]+x12*w1[5]
          + x20*w1[6]+x21*w1[7]+x22*w1[8];
      const float* wap = wa + cb*32 + ci;
      #pragma unroll
      for (int co=0;co<8;co++) acc[co] += x11 * wap[co*32];
    }
    const int l = (by*4+iy)*HW_ + bx*16+ix;
    *(float2*)(xq + lane*8 + co0) = float2{a0,a1};
    uint4 vv;
    vv.x = pkbf(acc[0],acc[1]); vv.y = pkbf(acc[2],acc[3]);
    vv.z = pkbf(acc[4],acc[5]); vv.w = pkbf(acc[6],acc[7]);
    *(uint4*)(Vu + (size_t)l*32 + cb) = vv;
  }
  __syncthreads();

  // pack Ku/Qu rows (t<64: one pixel each)
  if (t < 64){
    const int ly = t >> 4, lx = t & 15;
    const int lp = (by*4+ly)*HW_ + bx*16+lx;
    const float4* qp = (const float4*)(xq + t*8);
    float4 a = qp[0], b = qp[1];
    float n2 = a.x*a.x+a.y*a.y+a.z*a.z+a.w*a.w
             + b.x*b.x+b.y*b.y+b.z*b.z+b.w*b.w;
    float sc = 1.0f / fmaxf(sqrtf(n2), 5e-5f);
    uint4 kk, qq;
    kk.x = pkbf(a.x*sc,a.y*sc); kk.y = pkbf(a.z*sc,a.w*sc);
    kk.z = pkbf(b.x*sc,b.y*sc); kk.w = pkbf(b.z*sc,b.w*sc);
    qq.x = pkbf(a.x,a.y); qq.y = pkbf(a.z,a.w);
    qq.z = pkbf(b.x,b.y); qq.w = pkbf(b.z,b.w);
    *(uint4*)(Ku + (size_t)lp*8) = kk;
    *(uint4*)(Qu + (size_t)lp*8) = qq;
  }

  // hash: px = lane, h = wave id (wave-uniform rot access)
  if (t < 256){
    const int h = __builtin_amdgcn_readfirstlane(t>>6);
    const float4* qp = (const float4*)(xq + lane*8);
    float4 qa = qp[0], qb = qp[1];
    float best = -INFINITY; int bi = 0;
    float worst = INFINITY; int wi = 0;
    for (int i=0; i<64; i++){
      const float* rp = rot + h*64 + i;   // rot[f*256 + h*64 + i]
      float v = qa.x*rp[0]    + qa.y*rp[256]  + qa.z*rp[512]  + qa.w*rp[768]
              + qb.x*rp[1024] + qb.y*rp[1280] + qb.z*rp[1536] + qb.w*rp[1792];
      if (v > best)  { best  = v; bi = i; }
      if (v < worst) { worst = v; wi = i; }
    }
    int c = (-worst > best) ? (64+wi) : bi;
    const int ly = lane >> 4, lx = lane & 15;
    const int lpix = (by*4+ly)*HW_ + bx*16+lx;
    code[h*LTOT + lpix] = c;
    atomicAdd(&hist[(h*NSEG + (lpix>>8))*NBUCK + c], 1);
  }
  __syncthreads();
}

// ---------------- phase 2: per-block scan (from hist) + ballot rank ----------------
__device__ __forceinline__ void phase_spos(const int* __restrict__ code,
    const int* __restrict__ hist, int* __restrict__ spos,
    int u, int t, SMu& sm)
{
  const int h = u / NSEG, seg = u - h*NSEG;
  const int l = seg*256 + t;
  int c = 0;
  if (t < 256) c = code[h*LTOT + l];

  if (t < 256){
    const int b = t & 127, gg = t >> 7;
    int pre = 0, tt = 0;
    const int sA = gg*72;
    for (int s = sA; s < sA+72; s++){
      int v = hist[(h*NSEG+s)*NBUCK + b];
      tt += v;
      if (s < seg) pre += v;
    }
    sm.s.pre2[gg][b] = pre; sm.s.tot2[gg][b] = tt;
  }
  const int lane = t & 63, w = t >> 6;
  u64 mask = ~0ull;
  #pragma unroll
  for (int bit=0; bit<7; bit++){
    u64 bset = __ballot((c>>bit)&1);
    mask &= ((c>>bit)&1) ? bset : ~bset;
  }
  int rin = __popcll(mask & ((lane==0)?0ull:(~0ull >> (64-lane))));
  int cnt = __popcll(mask);
  if (t < 256){ ((int*)sm.s.wh)[t] = 0; ((int*)sm.s.wh)[t+256] = 0; }
  __syncthreads();

  if (t < 256 && rin == 0) sm.s.wh[w][c] = cnt;
  if (t < NBUCK){
    int tt = sm.s.tot2[0][t] + sm.s.tot2[1][t];
    int v = tt;
    #pragma unroll
    for (int off=1; off<64; off<<=1){
      int uu = __shfl_up(v, off);
      if ((t & 63) >= off) v += uu;
    }
    sm.s.scv[t] = v;
  }
  __syncthreads();

  if (t < NBUCK){
    int tt = sm.s.tot2[0][t] + sm.s.tot2[1][t];
    int excl = sm.s.scv[t] - tt + ((t >= 64) ? sm.s.scv[63] : 0);
    sm.s.segbase[t] = excl + sm.s.pre2[0][t] + sm.s.pre2[1][t];
  }
  __syncthreads();

  if (t < 256){
    int r = sm.s.segbase[c] + rin;
    for (int ww=0; ww<w; ww++) r += sm.s.wh[ww][c];
    spos[h*LTOT + r] = l;
  }
  __syncthreads();
}

// ---------------- phase 3: chunked attention (gather-staged via spos) ----------------
__device__ __forceinline__ void phase_attn(const u16* __restrict__ Ku,
    const u16* __restrict__ Qu, const u16* __restrict__ Vu,
    const int* __restrict__ spos, u16* __restrict__ ret_u, float* __restrict__ bs_u,
    int u, int t, SMu& sm)
{
  const int k = u & (NCHUNK-1), h = u >> 8;
  u16* Klds = sm.a.Klds;
  u16* Qlds = sm.a.Qlds;
  float* qn = sm.a.qn;
  int* spos_l = sm.a.spos_l;

  if (t < CHU){
    int pos0 = spos[h*LTOT + k*CHU + t];
    spos_l[t] = pos0;
    uint4 qv = *(const uint4*)(Qu + (size_t)pos0*8);
    *(uint4*)(Qlds + t*8) = qv;
    float f0=bflo(qv.x), f1=bfhi(qv.x), f2=bflo(qv.y), f3=bfhi(qv.y);
    float f4=bflo(qv.z), f5=bfhi(qv.z), f6=bflo(qv.w), f7=bfhi(qv.w);
    qn[t] = sqrtf(f0*f0+f1*f1+f2*f2+f3*f3+f4*f4+f5*f5+f6*f6+f7*f7)*1.01f + 1e-6f;
    #pragma unroll
    for (int rr=0; rr<3; rr++){
      const int gkb = ((k + NCHUNK-1 + rr) & (NCHUNK-1)) * CHU;
      int pk = spos[h*LTOT + gkb + t];
      *(uint4*)(Klds + (rr*CHU + t)*8) = *(const uint4*)(Ku + (size_t)pk*8);
    }
  }
  for (int j = t; j < 432; j += 320){
    int p = j >> 1, hf = j & 1;
    int g = 2*p;
    int rg = g / CHU, lk = g - rg*CHU;
    const int gkb = ((k + NCHUNK-1 + rg) & (NCHUNK-1)) * CHU;
    int posA = spos[h*LTOT + gkb + lk];
    int posB = spos[h*LTOT + gkb + lk + 1];
    const uint4* ra = (const uint4*)(Vu + (size_t)posA*32);
    const uint4* rb = (const uint4*)(Vu + (size_t)posB*32);
    uint4 A0 = ra[hf*2], A1 = ra[hf*2+1];
    uint4 B0 = rb[hf*2], B1 = rb[hf*2+1];
    u32 aw[8] = {A0.x,A0.y,A0.z,A0.w,A1.x,A1.y,A1.z,A1.w};
    u32 bw[8] = {B0.x,B0.y,B0.z,B0.w,B1.x,B1.y,B1.z,B1.w};
    int ebase = hf*16;
    u16* vtb = (u16*)sm.a.VT[rg];
    #pragma unroll
    for (int m=0;m<8;m++){
      u32 al = aw[m]&0xffffu, ah = aw[m]>>16;
      u32 bl = bw[m]&0xffffu, bh = bw[m]>>16;
      *(u32*)&vtb[(ebase+2*m  )*VTS + lk] = al | (bl<<16);
      *(u32*)&vtb[(ebase+2*m+1)*VTS + lk] = ah | (bh<<16);
    }
  }
  __syncthreads();

  const int lane = t & 63;
  const int wv = t >> 6;                 // 0..4
  const int q = lane & 15;
  const int quad = lane >> 4;
  const bool two = (wv < 4);
  const int tl0 = 2*wv;
  const int tl1 = two ? (2*wv+1) : 8;

  const short4v zs = {0,0,0,0};
  short4v bq0 = zs, bq1 = zs;
  if (quad < 2){
    bq0 = *(const short4v*)(Qlds + (tl0*16+q)*8 + quad*4);
    if (two) bq1 = *(const short4v*)(Qlds + (tl1*16+q)*8 + quad*4);
  }
  const float m0 = qn[tl0*16+q];
  const float m1 = two ? qn[tl1*16+q] : 0.f;

  f32x4 o00={0,0,0,0}, o01={0,0,0,0}, o10={0,0,0,0}, o11={0,0,0,0};
  float s0 = 0.f, s1 = 0.f;

  #pragma unroll 3
  for (int kt=0; kt<27; kt++){
    const int rg = kt / 9, ktl = kt - rg*9;
    const u16* vtb = sm.a.VT[rg];
    short4v av = zs;
    if (quad < 2) av = *(const short4v*)(Klds + (kt*16+q)*8 + quad*4);
    f32x4 zc = {0.f,0.f,0.f,0.f};
    f32x4 stA = __builtin_amdgcn_mfma_f32_16x16x16bf16_1k(av, bq0, zc, 0,0,0);

    float pA0 = __expf(stA[0]-m0), pA1 = __expf(stA[1]-m0);
    float pA2 = __expf(stA[2]-m0), pA3 = __expf(stA[3]-m0);
    s0 += (pA0+pA1)+(pA2+pA3);
    union { u32 u[2]; short4v s4; } pkA;
    pkA.u[0] = pkbf(pA0,pA1); pkA.u[1] = pkbf(pA2,pA3);

    short4v va0 = *(const short4v*)(&vtb[ q    *VTS + ktl*16 + quad*4]);
    short4v va1 = *(const short4v*)(&vtb[(q+16)*VTS + ktl*16 + quad*4]);
    o00 = __builtin_amdgcn_mfma_f32_16x16x16bf16_1k(va0, pkA.s4, o00, 0,0,0);
    o01 = __builtin_amdgcn_mfma_f32_16x16x16bf16_1k(va1, pkA.s4, o01, 0,0,0);

    if (two){
      f32x4 stB = __builtin_amdgcn_mfma_f32_16x16x16bf16_1k(av, bq1, zc, 0,0,0);
      float pB0 = __expf(stB[0]-m1), pB1 = __expf(stB[1]-m1);
      float pB2 = __expf(stB[2]-m1), pB3 = __expf(stB[3]-m1);
      s1 += (pB0+pB1)+(pB2+pB3);
      union { u32 u[2]; short4v s4; } pkB;
      pkB.u[0] = pkbf(pB0,pB1); pkB.u[1] = pkbf(pB2,pB3);
      o10 = __builtin_amdgcn_mfma_f32_16x16x16bf16_1k(va0, pkB.s4, o10, 0,0,0);
      o11 = __builtin_amdgcn_mfma_f32_16x16x16bf16_1k(va1, pkB.s4, o11, 0,0,0);
    }
  }

  float st0 = s0;
  st0 += __shfl_xor(st0, 16); st0 += __shfl_xor(st0, 32);
  float inv0 = 1.0f/st0;

  const int pos0 = spos_l[tl0*16 + q];
  u16* rp0 = ret_u + (size_t)(h*LTOT + pos0)*32;
  uint2 wA, wB;
  wA.x = pkbf(o00[0]*inv0, o00[1]*inv0); wA.y = pkbf(o00[2]*inv0, o00[3]*inv0);
  wB.x = pkbf(o01[0]*inv0, o01[1]*inv0); wB.y = pkbf(o01[2]*inv0, o01[3]*inv0);
  *(uint2*)&rp0[quad*4]    = wA;
  *(uint2*)&rp0[16+quad*4] = wB;
  if (quad == 0) bs_u[h*LTOT + pos0] = m0 + __logf(st0);

  if (two){
    float st1 = s1;
    st1 += __shfl_xor(st1, 16); st1 += __shfl_xor(st1, 32);
    float inv1 = 1.0f/st1;
    const int pos1 = spos_l[tl1*16 + q];
    u16* rp1 = ret_u + (size_t)(h*LTOT + pos1)*32;
    wA.x = pkbf(o10[0]*inv1, o10[1]*inv1); wA.y = pkbf(o10[2]*inv1, o10[3]*inv1);
    wB.x = pkbf(o11[0]*inv1, o11[1]*inv1); wB.y = pkbf(o11[2]*inv1, o11[3]*inv1);
    *(uint2*)&rp1[quad*4]    = wA;
    *(uint2*)&rp1[16+quad*4] = wB;
    if (quad == 0) bs_u[h*LTOT + pos1] = m1 + __logf(st1);
  }
  __syncthreads();
}

// ---------------- phase 4: cross-hash softmax + residual ----------------
__device__ __forceinline__ void phase_final(const float* __restrict__ x,
    const u16* __restrict__ ret_u, const float* __restrict__ bs_u,
    float* __restrict__ out, int u, int t)
{
  if (t >= 256) return;
  const int l  = u*64 + (t & 63);
  const int eg = t >> 6;
  float bs[NH];
  #pragma unroll
  for (int h=0;h<NH;h++) bs[h] = bs_u[h*LTOT + l];
  float m = fmaxf(fmaxf(bs[0],bs[1]), fmaxf(bs[2],bs[3]));
  float p[NH]; float s = 0.f;
  #pragma unroll
  for (int h=0;h<NH;h++){ p[h] = __expf(bs[h]-m); s += p[h]; }
  float inv = 1.0f/s;
  float o[8];
  #pragma unroll
  for (int e=0;e<8;e++) o[e]=0.f;
  #pragma unroll
  for (int h=0;h<NH;h++){
    float w = p[h]*inv;
    uint4 v = *(const uint4*)(ret_u + (size_t)(h*LTOT + l)*32 + eg*8);
    o[0] += w*bflo(v.x); o[1] += w*bfhi(v.x);
    o[2] += w*bflo(v.y); o[3] += w*bfhi(v.y);
    o[4] += w*bflo(v.z); o[5] += w*bfhi(v.z);
    o[6] += w*bflo(v.w); o[7] += w*bfhi(v.w);
  }
  #pragma unroll
  for (int e=0;e<8;e++){
    int ge = eg*8 + e;
    out[ge*LTOT + l] = o[e] + x[ge*LTOT + l];
  }
}

// ---------------- fused cooperative kernel ----------------
__global__ __launch_bounds__(320) void k_fused(const float* __restrict__ x,
    const float* __restrict__ wm, const float* __restrict__ bm,
    const float* __restrict__ wa, const float* __restrict__ ba,
    const float* __restrict__ rot,
    u16* __restrict__ Ku, u16* __restrict__ Qu, u16* __restrict__ Vu,
    int* __restrict__ code, int* __restrict__ hist, int* __restrict__ spos,
    u16* __restrict__ ret_u, float* __restrict__ bs_u, float* __restrict__ out)
{
  __shared__ SMu sm;
  cg::grid_group grid = cg::this_grid();
  const int t = threadIdx.x;
  const int bid = blockIdx.x;
  const int nb = gridDim.x;

  phase_zero(bid*320 + t, nb*320, hist);
  grid.sync();
  for (int u = bid; u < 576; u += nb)
    phase_conv(x, wm, bm, wa, ba, rot, Ku, Qu, Vu, code, hist, u, t, sm);
  grid.sync();
  for (int u = bid; u < NH*NSEG; u += nb)
    phase_spos(code, hist, spos, u, t, sm);
  grid.sync();
  for (int u = bid; u < NCHUNK*NH; u += nb)
    phase_attn(Ku, Qu, Vu, spos, ret_u, bs_u, u, t, sm);
  grid.sync();
  for (int u = bid; u < 576; u += nb)
    phase_final(x, ret_u, bs_u, out, u, t);
}

// ---------------- legacy fallback kernels (same phase code, 4 launches) ----------------
__global__ __launch_bounds__(320) void k_conv_l(const float* __restrict__ x,
    const float* __restrict__ wm, const float* __restrict__ bm,
    const float* __restrict__ wa, const float* __restrict__ ba,
    const float* __restrict__ rot,
    u16* __restrict__ Ku, u16* __restrict__ Qu, u16* __restrict__ Vu,
    int* __restrict__ code, int* __restrict__ hist)
{
  __shared__ SMu sm;
  phase_conv(x, wm, bm, wa, ba, rot, Ku, Qu, Vu, code, hist, blockIdx.x, threadIdx.x, sm);
}
__global__ __launch_bounds__(320) void k_spos_l(const int* __restrict__ code,
    const int* __restrict__ hist, int* __restrict__ spos)
{
  __shared__ SMu sm;
  phase_spos(code, hist, spos, blockIdx.x, threadIdx.x, sm);
}
__global__ __launch_bounds__(320) void k_attn_l(const u16* __restrict__ Ku,
    const u16* __restrict__ Qu, const u16* __restrict__ Vu,
    const int* __restrict__ spos, u16* __restrict__ ret_u, float* __restrict__ bs_u)
{
  __shared__ SMu sm;
  phase_attn(Ku, Qu, Vu, spos, ret_u, bs_u, blockIdx.x, threadIdx.x, sm);
}
__global__ __launch_bounds__(320) void k_final_l(const float* __restrict__ x,
    const u16* __restrict__ ret_u, const float* __restrict__ bs_u,
    float* __restrict__ out)
{
  phase_final(x, ret_u, bs_u, out, blockIdx.x, threadIdx.x);
}

extern "C" void kernel_launch(void* const* d_in, const int* in_sizes, int n_in,
                              void* d_out, int out_size, void* d_ws, size_t ws_size,
                              hipStream_t stream)
{
  const float* x   = (const float*)d_in[0];
  const float* wm  = (const float*)d_in[1];
  const float* bm  = (const float*)d_in[2];
  const float* wa  = (const float*)d_in[3];
  const float* ba  = (const float*)d_in[4];
  const float* rot = (const float*)d_in[5];
  float* out = (float*)d_out;

  char* ws = (char*)d_ws;
  size_t off = 0;
  auto alloc = [&](size_t bytes)->void*{
    void* p = ws + off;
    off = (off + bytes + 255) & ~(size_t)255;
    return p;
  };
  u16*   Ku     = (u16*)  alloc((size_t)LTOT*8*2);
  u16*   Qu     = (u16*)  alloc((size_t)LTOT*8*2);
  u16*   Vu     = (u16*)  alloc((size_t)LTOT*32*2);
  int*   code   = (int*)  alloc((size_t)NH*LTOT*4);
  int*   hist   = (int*)  alloc((size_t)NH*NSEG*NBUCK*4);
  int*   spos   = (int*)  alloc((size_t)NH*LTOT*4);
  u16*   ret_u  = (u16*)  alloc((size_t)NH*LTOT*32*2);
  float* bs_u   = (float*)alloc((size_t)NH*LTOT*4);

  // Size the cooperative grid from actual occupancy (LDS union 38.8 KB -> expect 4/CU -> 1024).
  static int coop_blocks = -1;
  if (coop_blocks < 0){
    int occ = 0;
    hipError_t qe = hipOccupancyMaxActiveBlocksPerMultiprocessor(&occ, (const void*)k_fused, 320, 0);
    if (qe != hipSuccess || occ < 1) occ = 1;
    int nb = occ * 256;
    if (nb > NCHUNK*NH) nb = NCHUNK*NH;   // never need more than the attn unit count
    coop_blocks = nb;
  }

  hipError_t e = hipLaunchCooperativeKernel((const void*)k_fused,
      dim3(coop_blocks), dim3(320),
      (void**)(void*[]){ (void*)&x, (void*)&wm, (void*)&bm, (void*)&wa, (void*)&ba, (void*)&rot,
                         (void*)&Ku, (void*)&Qu, (void*)&Vu, (void*)&code, (void*)&hist, (void*)&spos,
                         (void*)&ret_u, (void*)&bs_u, (void*)&out },
      0, stream);

  if (e != hipSuccess){
    (void)hipGetLastError();   // clear sticky error; fall back to legacy 4-kernel path
    hipMemsetAsync(hist, 0, (size_t)NH*NSEG*NBUCK*4, stream);
    hipLaunchKernelGGL(k_conv_l,  dim3(576),        dim3(320), 0, stream, x, wm, bm, wa, ba, rot, Ku, Qu, Vu, code, hist);
    hipLaunchKernelGGL(k_spos_l,  dim3(NSEG*NH),    dim3(320), 0, stream, code, hist, spos);
    hipLaunchKernelGGL(k_attn_l,  dim3(NCHUNK*NH),  dim3(320), 0, stream, Ku, Qu, Vu, spos, ret_u, bs_u);
    hipLaunchKernelGGL(k_final_l, dim3(576),        dim3(320), 0, stream, x, ret_u, bs_u, out);
  }
}

// Round 2
// 365.272 us; speedup vs baseline: 1.0065x; 1.0065x over previous
//
#include <hip/hip_runtime.h>
#include <hip/hip_bf16.h>
#include <hip/hip_cooperative_groups.h>
#include <math.h>

namespace cg = cooperative_groups;

#define LTOT 36864      // 192*192
#define NH 4
#define NCHUNK 256
#define CHU 144
#define NBUCK 128
#define NSEG 144        // 36864 / 256
#define HW_ 192
#define VTS 148         // VT row stride (u16)

typedef unsigned int u32;
typedef unsigned short u16;
typedef unsigned long long u64;
typedef __attribute__((ext_vector_type(4))) short short4v;
typedef __attribute__((ext_vector_type(4))) float f32x4;

__device__ __forceinline__ u32 pkbf(float a, float b){
  union { __hip_bfloat162 h2; u32 u; } cv;
  cv.h2 = __float22bfloat162_rn(float2{a,b});
  return cv.u;
}
__device__ __forceinline__ float bflo(u32 w){ return __uint_as_float(w<<16); }
__device__ __forceinline__ float bfhi(u32 w){ return __uint_as_float(w & 0xffff0000u); }

// Shared-memory union for the fused kernel (max = attn: 38784 B -> 4 blocks/CU)
union __align__(16) SMu {
  struct { float xs[32*108]; float xq[64*8]; } c;                       // 15872 B
  struct { u16 Klds[432*8]; u16 Qlds[CHU*8]; u16 VT[3][32*VTS];
           float qn[CHU]; int spos_l[CHU]; } a;                          // 38784 B
  struct { int pre2[2][NBUCK]; int tot2[2][NBUCK]; int scv[NBUCK];
           int segbase[NBUCK]; int wh[4][NBUCK]; } s;                    // 5120 B
};

// ---------------- phase 0: zero hist ----------------
__device__ __forceinline__ void phase_zero(int gid, int gsize, int* __restrict__ hist){
  for (int i = gid; i < NH*NSEG*NBUCK; i += gsize) hist[i] = 0;
}

// ---------------- phase 1: conv + hash + hist + bf16 K/Q/V pack ----------------
__device__ __forceinline__ void phase_conv(const float* __restrict__ x,
    const float* __restrict__ wm, const float* __restrict__ bm,
    const float* __restrict__ wa, const float* __restrict__ ba,
    const float* __restrict__ rot,
    u16* __restrict__ Ku, u16* __restrict__ Qu, u16* __restrict__ Vu,
    int* __restrict__ code, int* __restrict__ hist,
    int id, int t, SMu& sm)
{
  float* xs = sm.c.xs;
  float* xq = sm.c.xq;
  const int bx = id % 12, by = id / 12;

  for (int idx=t; idx<3456; idx+=320){
    int ci = idx/108, rem = idx-ci*108;
    int iy = rem/18,  ix = rem-iy*18;
    int yy = by*4+iy-1, xx = bx*16+ix-1;
    float v = 0.f;
    if (yy>=0 && yy<HW_ && xx>=0 && xx<HW_) v = x[ci*LTOT + yy*HW_ + xx];
    xs[idx] = v;
  }
  __syncthreads();
  const int lane = t & 63;
  if (t < 256){
    const int w  = __builtin_amdgcn_readfirstlane(t>>6);
    const int co0 = 2*w, cb = 8*w;
    const int ix = lane & 15, iy = lane >> 4;
    float a0 = bm[co0], a1 = bm[co0+1];
    float acc[8];
    #pragma unroll
    for (int co=0;co<8;co++) acc[co] = ba[cb+co];
    const float* xb  = xs + iy*18 + ix;
    const float* w0p = wm + co0*288;
    const float* w1p = w0p + 288;
    for (int ci=0; ci<32; ci++){
      const float* xp = xb + ci*108;
      float x00=xp[0],  x01=xp[1],  x02=xp[2];
      float x10=xp[18], x11=xp[19], x12=xp[20];
      float x20=xp[36], x21=xp[37], x22=xp[38];
      const float* w0 = w0p + ci*9;
      const float* w1 = w1p + ci*9;
      a0 += x00*w0[0]+x01*w0[1]+x02*w0[2]
          + x10*w0[3]+x11*w0[4]+x12*w0[5]
          + x20*w0[6]+x21*w0[7]+x22*w0[8];
      a1 += x00*w1[0]+x01*w1[1]+x02*w1[2]
          + x10*w1[3]+x11*w1[4]+x12*w1[5]
          + x20*w1[6]+x21*w1[7]+x22*w1[8];
      const float* wap = wa + cb*32 + ci;
      #pragma unroll
      for (int co=0;co<8;co++) acc[co] += x11 * wap[co*32];
    }
    const int l = (by*4+iy)*HW_ + bx*16+ix;
    *(float2*)(xq + lane*8 + co0) = float2{a0,a1};
    uint4 vv;
    vv.x = pkbf(acc[0],acc[1]); vv.y = pkbf(acc[2],acc[3]);
    vv.z = pkbf(acc[4],acc[5]); vv.w = pkbf(acc[6],acc[7]);
    *(uint4*)(Vu + (size_t)l*32 + cb) = vv;
  }
  __syncthreads();

  if (t < 64){
    const int ly = t >> 4, lx = t & 15;
    const int lp = (by*4+ly)*HW_ + bx*16+lx;
    const float4* qp = (const float4*)(xq + t*8);
    float4 a = qp[0], b = qp[1];
    float n2 = a.x*a.x+a.y*a.y+a.z*a.z+a.w*a.w
             + b.x*b.x+b.y*b.y+b.z*b.z+b.w*b.w;
    float sc = 1.0f / fmaxf(sqrtf(n2), 5e-5f);
    uint4 kk, qq;
    kk.x = pkbf(a.x*sc,a.y*sc); kk.y = pkbf(a.z*sc,a.w*sc);
    kk.z = pkbf(b.x*sc,b.y*sc); kk.w = pkbf(b.z*sc,b.w*sc);
    qq.x = pkbf(a.x,a.y); qq.y = pkbf(a.z,a.w);
    qq.z = pkbf(b.x,b.y); qq.w = pkbf(b.z,b.w);
    *(uint4*)(Ku + (size_t)lp*8) = kk;
    *(uint4*)(Qu + (size_t)lp*8) = qq;
  }

  if (t < 256){
    const int h = __builtin_amdgcn_readfirstlane(t>>6);
    const float4* qp = (const float4*)(xq + lane*8);
    float4 qa = qp[0], qb = qp[1];
    float best = -INFINITY; int bi = 0;
    float worst = INFINITY; int wi = 0;
    for (int i=0; i<64; i++){
      const float* rp = rot + h*64 + i;   // rot[f*256 + h*64 + i]
      float v = qa.x*rp[0]    + qa.y*rp[256]  + qa.z*rp[512]  + qa.w*rp[768]
              + qb.x*rp[1024] + qb.y*rp[1280] + qb.z*rp[1536] + qb.w*rp[1792];
      if (v > best)  { best  = v; bi = i; }
      if (v < worst) { worst = v; wi = i; }
    }
    int c = (-worst > best) ? (64+wi) : bi;
    const int ly = lane >> 4, lx = lane & 15;
    const int lpix = (by*4+ly)*HW_ + bx*16+lx;
    code[h*LTOT + lpix] = c;
    atomicAdd(&hist[(h*NSEG + (lpix>>8))*NBUCK + c], 1);
  }
  __syncthreads();
}

// ---------------- phase 2: per-block scan + ballot rank ----------------
__device__ __forceinline__ void phase_spos(const int* __restrict__ code,
    const int* __restrict__ hist, int* __restrict__ spos,
    int u, int t, SMu& sm)
{
  const int h = u / NSEG, seg = u - h*NSEG;
  const int l = seg*256 + t;
  int c = 0;
  if (t < 256) c = code[h*LTOT + l];

  if (t < 256){
    const int b = t & 127, gg = t >> 7;
    int pre = 0, tt = 0;
    const int sA = gg*72;
    for (int s = sA; s < sA+72; s++){
      int v = hist[(h*NSEG+s)*NBUCK + b];
      tt += v;
      if (s < seg) pre += v;
    }
    sm.s.pre2[gg][b] = pre; sm.s.tot2[gg][b] = tt;
  }
  const int lane = t & 63, w = t >> 6;
  u64 mask = ~0ull;
  #pragma unroll
  for (int bit=0; bit<7; bit++){
    u64 bset = __ballot((c>>bit)&1);
    mask &= ((c>>bit)&1) ? bset : ~bset;
  }
  int rin = __popcll(mask & ((lane==0)?0ull:(~0ull >> (64-lane))));
  int cnt = __popcll(mask);
  if (t < 256){ ((int*)sm.s.wh)[t] = 0; ((int*)sm.s.wh)[t+256] = 0; }
  __syncthreads();

  if (t < 256 && rin == 0) sm.s.wh[w][c] = cnt;
  if (t < NBUCK){
    int tt = sm.s.tot2[0][t] + sm.s.tot2[1][t];
    int v = tt;
    #pragma unroll
    for (int off=1; off<64; off<<=1){
      int uu = __shfl_up(v, off);
      if ((t & 63) >= off) v += uu;
    }
    sm.s.scv[t] = v;
  }
  __syncthreads();

  if (t < NBUCK){
    int tt = sm.s.tot2[0][t] + sm.s.tot2[1][t];
    int excl = sm.s.scv[t] - tt + ((t >= 64) ? sm.s.scv[63] : 0);
    sm.s.segbase[t] = excl + sm.s.pre2[0][t] + sm.s.pre2[1][t];
  }
  __syncthreads();

  if (t < 256){
    int r = sm.s.segbase[c] + rin;
    for (int ww=0; ww<w; ww++) r += sm.s.wh[ww][c];
    spos[h*LTOT + r] = l;
  }
  __syncthreads();
}

// ---------------- phase 3: chunked attention ----------------
__device__ __forceinline__ void phase_attn(const u16* __restrict__ Ku,
    const u16* __restrict__ Qu, const u16* __restrict__ Vu,
    const int* __restrict__ spos, u16* __restrict__ ret_u, float* __restrict__ bs_u,
    int u, int t, SMu& sm)
{
  const int k = u & (NCHUNK-1), h = u >> 8;
  u16* Klds = sm.a.Klds;
  u16* Qlds = sm.a.Qlds;
  float* qn = sm.a.qn;
  int* spos_l = sm.a.spos_l;

  if (t < CHU){
    int pos0 = spos[h*LTOT + k*CHU + t];
    spos_l[t] = pos0;
    uint4 qv = *(const uint4*)(Qu + (size_t)pos0*8);
    *(uint4*)(Qlds + t*8) = qv;
    float f0=bflo(qv.x), f1=bfhi(qv.x), f2=bflo(qv.y), f3=bfhi(qv.y);
    float f4=bflo(qv.z), f5=bfhi(qv.z), f6=bflo(qv.w), f7=bfhi(qv.w);
    qn[t] = sqrtf(f0*f0+f1*f1+f2*f2+f3*f3+f4*f4+f5*f5+f6*f6+f7*f7)*1.01f + 1e-6f;
    #pragma unroll
    for (int rr=0; rr<3; rr++){
      const int gkb = ((k + NCHUNK-1 + rr) & (NCHUNK-1)) * CHU;
      int pk = spos[h*LTOT + gkb + t];
      *(uint4*)(Klds + (rr*CHU + t)*8) = *(const uint4*)(Ku + (size_t)pk*8);
    }
  }
  for (int j = t; j < 432; j += 320){
    int p = j >> 1, hf = j & 1;
    int g = 2*p;
    int rg = g / CHU, lk = g - rg*CHU;
    const int gkb = ((k + NCHUNK-1 + rg) & (NCHUNK-1)) * CHU;
    int posA = spos[h*LTOT + gkb + lk];
    int posB = spos[h*LTOT + gkb + lk + 1];
    const uint4* ra = (const uint4*)(Vu + (size_t)posA*32);
    const uint4* rb = (const uint4*)(Vu + (size_t)posB*32);
    uint4 A0 = ra[hf*2], A1 = ra[hf*2+1];
    uint4 B0 = rb[hf*2], B1 = rb[hf*2+1];
    u32 aw[8] = {A0.x,A0.y,A0.z,A0.w,A1.x,A1.y,A1.z,A1.w};
    u32 bw[8] = {B0.x,B0.y,B0.z,B0.w,B1.x,B1.y,B1.z,B1.w};
    int ebase = hf*16;
    u16* vtb = (u16*)sm.a.VT[rg];
    #pragma unroll
    for (int m=0;m<8;m++){
      u32 al = aw[m]&0xffffu, ah = aw[m]>>16;
      u32 bl = bw[m]&0xffffu, bh = bw[m]>>16;
      *(u32*)&vtb[(ebase+2*m  )*VTS + lk] = al | (bl<<16);
      *(u32*)&vtb[(ebase+2*m+1)*VTS + lk] = ah | (bh<<16);
    }
  }
  __syncthreads();

  const int lane = t & 63;
  const int wv = t >> 6;                 // 0..4
  const int q = lane & 15;
  const int quad = lane >> 4;
  const bool two = (wv < 4);
  const int tl0 = 2*wv;
  const int tl1 = two ? (2*wv+1) : 8;

  const short4v zs = {0,0,0,0};
  short4v bq0 = zs, bq1 = zs;
  if (quad < 2){
    bq0 = *(const short4v*)(Qlds + (tl0*16+q)*8 + quad*4);
    if (two) bq1 = *(const short4v*)(Qlds + (tl1*16+q)*8 + quad*4);
  }
  const float m0 = qn[tl0*16+q];
  const float m1 = two ? qn[tl1*16+q] : 0.f;

  f32x4 o00={0,0,0,0}, o01={0,0,0,0}, o10={0,0,0,0}, o11={0,0,0,0};
  float s0 = 0.f, s1 = 0.f;

  #pragma unroll 3
  for (int kt=0; kt<27; kt++){
    const int rg = kt / 9, ktl = kt - rg*9;
    const u16* vtb = sm.a.VT[rg];
    short4v av = zs;
    if (quad < 2) av = *(const short4v*)(Klds + (kt*16+q)*8 + quad*4);
    f32x4 zc = {0.f,0.f,0.f,0.f};
    f32x4 stA = __builtin_amdgcn_mfma_f32_16x16x16bf16_1k(av, bq0, zc, 0,0,0);

    float pA0 = __expf(stA[0]-m0), pA1 = __expf(stA[1]-m0);
    float pA2 = __expf(stA[2]-m0), pA3 = __expf(stA[3]-m0);
    s0 += (pA0+pA1)+(pA2+pA3);
    union { u32 u[2]; short4v s4; } pkA;
    pkA.u[0] = pkbf(pA0,pA1); pkA.u[1] = pkbf(pA2,pA3);

    short4v va0 = *(const short4v*)(&vtb[ q    *VTS + ktl*16 + quad*4]);
    short4v va1 = *(const short4v*)(&vtb[(q+16)*VTS + ktl*16 + quad*4]);
    o00 = __builtin_amdgcn_mfma_f32_16x16x16bf16_1k(va0, pkA.s4, o00, 0,0,0);
    o01 = __builtin_amdgcn_mfma_f32_16x16x16bf16_1k(va1, pkA.s4, o01, 0,0,0);

    if (two){
      f32x4 stB = __builtin_amdgcn_mfma_f32_16x16x16bf16_1k(av, bq1, zc, 0,0,0);
      float pB0 = __expf(stB[0]-m1), pB1 = __expf(stB[1]-m1);
      float pB2 = __expf(stB[2]-m1), pB3 = __expf(stB[3]-m1);
      s1 += (pB0+pB1)+(pB2+pB3);
      union { u32 u[2]; short4v s4; } pkB;
      pkB.u[0] = pkbf(pB0,pB1); pkB.u[1] = pkbf(pB2,pB3);
      o10 = __builtin_amdgcn_mfma_f32_16x16x16bf16_1k(va0, pkB.s4, o10, 0,0,0);
      o11 = __builtin_amdgcn_mfma_f32_16x16x16bf16_1k(va1, pkB.s4, o11, 0,0,0);
    }
  }

  float st0 = s0;
  st0 += __shfl_xor(st0, 16); st0 += __shfl_xor(st0, 32);
  float inv0 = 1.0f/st0;

  const int pos0 = spos_l[tl0*16 + q];
  u16* rp0 = ret_u + (size_t)(h*LTOT + pos0)*32;
  uint2 wA, wB;
  wA.x = pkbf(o00[0]*inv0, o00[1]*inv0); wA.y = pkbf(o00[2]*inv0, o00[3]*inv0);
  wB.x = pkbf(o01[0]*inv0, o01[1]*inv0); wB.y = pkbf(o01[2]*inv0, o01[3]*inv0);
  *(uint2*)&rp0[quad*4]    = wA;
  *(uint2*)&rp0[16+quad*4] = wB;
  if (quad == 0) bs_u[h*LTOT + pos0] = m0 + __logf(st0);

  if (two){
    float st1 = s1;
    st1 += __shfl_xor(st1, 16); st1 += __shfl_xor(st1, 32);
    float inv1 = 1.0f/st1;
    const int pos1 = spos_l[tl1*16 + q];
    u16* rp1 = ret_u + (size_t)(h*LTOT + pos1)*32;
    wA.x = pkbf(o10[0]*inv1, o10[1]*inv1); wA.y = pkbf(o10[2]*inv1, o10[3]*inv1);
    wB.x = pkbf(o11[0]*inv1, o11[1]*inv1); wB.y = pkbf(o11[2]*inv1, o11[3]*inv1);
    *(uint2*)&rp1[quad*4]    = wA;
    *(uint2*)&rp1[16+quad*4] = wB;
    if (quad == 0) bs_u[h*LTOT + pos1] = m1 + __logf(st1);
  }
  __syncthreads();
}

// ---------------- phase 4: cross-hash softmax + residual ----------------
__device__ __forceinline__ void phase_final(const float* __restrict__ x,
    const u16* __restrict__ ret_u, const float* __restrict__ bs_u,
    float* __restrict__ out, int u, int t)
{
  if (t >= 256) return;
  const int l  = u*64 + (t & 63);
  const int eg = t >> 6;
  float bs[NH];
  #pragma unroll
  for (int h=0;h<NH;h++) bs[h] = bs_u[h*LTOT + l];
  float m = fmaxf(fmaxf(bs[0],bs[1]), fmaxf(bs[2],bs[3]));
  float p[NH]; float s = 0.f;
  #pragma unroll
  for (int h=0;h<NH;h++){ p[h] = __expf(bs[h]-m); s += p[h]; }
  float inv = 1.0f/s;
  float o[8];
  #pragma unroll
  for (int e=0;e<8;e++) o[e]=0.f;
  #pragma unroll
  for (int h=0;h<NH;h++){
    float w = p[h]*inv;
    uint4 v = *(const uint4*)(ret_u + (size_t)(h*LTOT + l)*32 + eg*8);
    o[0] += w*bflo(v.x); o[1] += w*bfhi(v.x);
    o[2] += w*bflo(v.y); o[3] += w*bfhi(v.y);
    o[4] += w*bflo(v.z); o[5] += w*bfhi(v.z);
    o[6] += w*bflo(v.w); o[7] += w*bfhi(v.w);
  }
  #pragma unroll
  for (int e=0;e<8;e++){
    int ge = eg*8 + e;
    out[ge*LTOT + l] = o[e] + x[ge*LTOT + l];
  }
}

// ---------------- fused cooperative kernel: 5 waves/EU min -> VGPR<=102 -> 4 blocks/CU ----------------
__global__ __launch_bounds__(320, 5) void k_fused(const float* __restrict__ x,
    const float* __restrict__ wm, const float* __restrict__ bm,
    const float* __restrict__ wa, const float* __restrict__ ba,
    const float* __restrict__ rot,
    u16* __restrict__ Ku, u16* __restrict__ Qu, u16* __restrict__ Vu,
    int* __restrict__ code, int* __restrict__ hist, int* __restrict__ spos,
    u16* __restrict__ ret_u, float* __restrict__ bs_u, float* __restrict__ out)
{
  __shared__ SMu sm;
  cg::grid_group grid = cg::this_grid();
  const int t = threadIdx.x;
  const int bid = blockIdx.x;
  const int nb = gridDim.x;

  phase_zero(bid*320 + t, nb*320, hist);
  grid.sync();
  for (int u = bid; u < 576; u += nb)
    phase_conv(x, wm, bm, wa, ba, rot, Ku, Qu, Vu, code, hist, u, t, sm);
  grid.sync();
  for (int u = bid; u < NH*NSEG; u += nb)
    phase_spos(code, hist, spos, u, t, sm);
  grid.sync();
  for (int u = bid; u < NCHUNK*NH; u += nb)
    phase_attn(Ku, Qu, Vu, spos, ret_u, bs_u, u, t, sm);
  grid.sync();
  for (int u = bid; u < 576; u += nb)
    phase_final(x, ret_u, bs_u, out, u, t);
}

// ================= legacy fallback: byte-identical Round-0 baseline kernels =================
__global__ __launch_bounds__(256) void k_conv(const float* __restrict__ x,
    const float* __restrict__ wm, const float* __restrict__ bm,
    const float* __restrict__ wa, const float* __restrict__ ba,
    const float* __restrict__ rot,
    u16* __restrict__ Ku, u16* __restrict__ Qu, u16* __restrict__ Vu,
    int* __restrict__ code, int* __restrict__ hist)
{
  __shared__ float xs[32*108];
  __shared__ float xq[64*8];
  const int t = threadIdx.x;
  const int id = blockIdx.x;
  const int bx = id % 12, by = id / 12;

  for (int idx=t; idx<3456; idx+=256){
    int ci = idx/108, rem = idx-ci*108;
    int iy = rem/18,  ix = rem-iy*18;
    int yy = by*4+iy-1, xx = bx*16+ix-1;
    float v = 0.f;
    if (yy>=0 && yy<HW_ && xx>=0 && xx<HW_) v = x[ci*LTOT + yy*HW_ + xx];
    xs[idx] = v;
  }
  __syncthreads();
  const int lane = t & 63;
  const int w  = __builtin_amdgcn_readfirstlane(t>>6);
  const int co0 = 2*w, cb = 8*w;
  const int ix = lane & 15, iy = lane >> 4;
  float a0 = bm[co0], a1 = bm[co0+1];
  float acc[8];
  #pragma unroll
  for (int co=0;co<8;co++) acc[co] = ba[cb+co];
  const float* xb  = xs + iy*18 + ix;
  const float* w0p = wm + co0*288;
  const float* w1p = w0p + 288;
  for (int ci=0; ci<32; ci++){
    const float* xp = xb + ci*108;
    float x00=xp[0],  x01=xp[1],  x02=xp[2];
    float x10=xp[18], x11=xp[19], x12=xp[20];
    float x20=xp[36], x21=xp[37], x22=xp[38];
    const float* w0 = w0p + ci*9;
    const float* w1 = w1p + ci*9;
    a0 += x00*w0[0]+x01*w0[1]+x02*w0[2]
        + x10*w0[3]+x11*w0[4]+x12*w0[5]
        + x20*w0[6]+x21*w0[7]+x22*w0[8];
    a1 += x00*w1[0]+x01*w1[1]+x02*w1[2]
        + x10*w1[3]+x11*w1[4]+x12*w1[5]
        + x20*w1[6]+x21*w1[7]+x22*w1[8];
    const float* wap = wa + cb*32 + ci;
    #pragma unroll
    for (int co=0;co<8;co++) acc[co] += x11 * wap[co*32];
  }
  const int l = (by*4+iy)*HW_ + bx*16+ix;
  *(float2*)(xq + lane*8 + co0) = float2{a0,a1};
  uint4 vv;
  vv.x = pkbf(acc[0],acc[1]); vv.y = pkbf(acc[2],acc[3]);
  vv.z = pkbf(acc[4],acc[5]); vv.w = pkbf(acc[6],acc[7]);
  *(uint4*)(Vu + (size_t)l*32 + cb) = vv;
  __syncthreads();

  if (t < 64){
    const int ly = t >> 4, lx = t & 15;
    const int lp = (by*4+ly)*HW_ + bx*16+lx;
    const float4* qp = (const float4*)(xq + t*8);
    float4 a = qp[0], b = qp[1];
    float n2 = a.x*a.x+a.y*a.y+a.z*a.z+a.w*a.w
             + b.x*b.x+b.y*b.y+b.z*b.z+b.w*b.w;
    float sc = 1.0f / fmaxf(sqrtf(n2), 5e-5f);
    uint4 kk, qq;
    kk.x = pkbf(a.x*sc,a.y*sc); kk.y = pkbf(a.z*sc,a.w*sc);
    kk.z = pkbf(b.x*sc,b.y*sc); kk.w = pkbf(b.z*sc,b.w*sc);
    qq.x = pkbf(a.x,a.y); qq.y = pkbf(a.z,a.w);
    qq.z = pkbf(b.x,b.y); qq.w = pkbf(b.z,b.w);
    *(uint4*)(Ku + (size_t)lp*8) = kk;
    *(uint4*)(Qu + (size_t)lp*8) = qq;
  }

  {
    const int h = w;
    const float4* qp = (const float4*)(xq + lane*8);
    float4 qa = qp[0], qb = qp[1];
    float best = -INFINITY; int bi = 0;
    float worst = INFINITY; int wi = 0;
    for (int i=0; i<64; i++){
      const float* rp = rot + h*64 + i;
      float v = qa.x*rp[0]    + qa.y*rp[256]  + qa.z*rp[512]  + qa.w*rp[768]
              + qb.x*rp[1024] + qb.y*rp[1280] + qb.z*rp[1536] + qb.w*rp[1792];
      if (v > best)  { best  = v; bi = i; }
      if (v < worst) { worst = v; wi = i; }
    }
    int c = (-worst > best) ? (64+wi) : bi;
    const int ly = lane >> 4, lx = lane & 15;
    const int lpix = (by*4+ly)*HW_ + bx*16+lx;
    code[h*LTOT + lpix] = c;
    atomicAdd(&hist[(h*NSEG + (lpix>>8))*NBUCK + c], 1);
  }
}

__global__ __launch_bounds__(256) void k_spos(const int* __restrict__ code,
    const int* __restrict__ hist, int* __restrict__ spos)
{
  const int h = blockIdx.y, seg = blockIdx.x, t = threadIdx.x;
  const int l = seg*256 + t;
  int c = code[h*LTOT + l];

  __shared__ int pre2[2][NBUCK], tot2[2][NBUCK];
  __shared__ int scv[NBUCK];
  __shared__ int segbase[NBUCK];
  __shared__ int wh[4][NBUCK];

  {
    const int b = t & 127, gg = t >> 7;
    int pre = 0, tt = 0;
    const int sA = gg*72;
    for (int s = sA; s < sA+72; s++){
      int v = hist[(h*NSEG+s)*NBUCK + b];
      tt += v;
      if (s < seg) pre += v;
    }
    pre2[gg][b] = pre; tot2[gg][b] = tt;
  }
  const int lane = t & 63, w = t >> 6;
  u64 mask = ~0ull;
  #pragma unroll
  for (int bit=0; bit<7; bit++){
    u64 bset = __ballot((c>>bit)&1);
    mask &= ((c>>bit)&1) ? bset : ~bset;
  }
  int rin = __popcll(mask & ((lane==0)?0ull:(~0ull >> (64-lane))));
  int cnt = __popcll(mask);
  ((int*)wh)[t] = 0; ((int*)wh)[t+256] = 0;
  __syncthreads();

  if (rin == 0) wh[w][c] = cnt;
  if (t < NBUCK){
    int tt = tot2[0][t] + tot2[1][t];
    int v = tt;
    #pragma unroll
    for (int off=1; off<64; off<<=1){
      int u = __shfl_up(v, off);
      if ((t & 63) >= off) v += u;
    }
    scv[t] = v;
  }
  __syncthreads();

  if (t < NBUCK){
    int tt = tot2[0][t] + tot2[1][t];
    int excl = scv[t] - tt + ((t >= 64) ? scv[63] : 0);
    segbase[t] = excl + pre2[0][t] + pre2[1][t];
  }
  __syncthreads();

  int r = segbase[c] + rin;
  for (int ww=0; ww<w; ww++) r += wh[ww][c];
  spos[h*LTOT + r] = l;
}

__global__ __launch_bounds__(320) void k_attn(const u16* __restrict__ Ku,
    const u16* __restrict__ Qu, const u16* __restrict__ Vu,
    const int* __restrict__ spos, u16* __restrict__ ret_u, float* __restrict__ bs_u)
{
  __shared__ SMu sm;
  // reuse phase body with original grid mapping
  const int u = blockIdx.y*NCHUNK + blockIdx.x;
  phase_attn(Ku, Qu, Vu, spos, ret_u, bs_u, u, threadIdx.x, sm);
}

__global__ __launch_bounds__(256) void k_final(const float* __restrict__ x,
    const u16* __restrict__ ret_u, const float* __restrict__ bs_u,
    float* __restrict__ out)
{
  phase_final(x, ret_u, bs_u, out, blockIdx.x, threadIdx.x);
}

extern "C" void kernel_launch(void* const* d_in, const int* in_sizes, int n_in,
                              void* d_out, int out_size, void* d_ws, size_t ws_size,
                              hipStream_t stream)
{
  const float* x   = (const float*)d_in[0];
  const float* wm  = (const float*)d_in[1];
  const float* bm  = (const float*)d_in[2];
  const float* wa  = (const float*)d_in[3];
  const float* ba  = (const float*)d_in[4];
  const float* rot = (const float*)d_in[5];
  float* out = (float*)d_out;

  char* ws = (char*)d_ws;
  size_t off = 0;
  auto alloc = [&](size_t bytes)->void*{
    void* p = ws + off;
    off = (off + bytes + 255) & ~(size_t)255;
    return p;
  };
  u16*   Ku     = (u16*)  alloc((size_t)LTOT*8*2);
  u16*   Qu     = (u16*)  alloc((size_t)LTOT*8*2);
  u16*   Vu     = (u16*)  alloc((size_t)LTOT*32*2);
  int*   code   = (int*)  alloc((size_t)NH*LTOT*4);
  int*   hist   = (int*)  alloc((size_t)NH*NSEG*NBUCK*4);
  int*   spos   = (int*)  alloc((size_t)NH*LTOT*4);
  u16*   ret_u  = (u16*)  alloc((size_t)NH*LTOT*32*2);
  float* bs_u   = (float*)alloc((size_t)NH*LTOT*4);

  // Cooperative grid: launch_bounds(320,5) guarantees 4 blocks/CU (VGPR<=102, LDS 38.8KB).
  static int coop_blocks = -2;   // -2 = unqueried, -1 = unusable
  if (coop_blocks == -2){
    int occ = 0;
    hipError_t qe = hipOccupancyMaxActiveBlocksPerMultiprocessor(&occ, (const void*)k_fused, 320, 0);
    if (qe != hipSuccess || occ < 1) coop_blocks = -1;
    else {
      int nb = occ * 256;
      if (nb > NCHUNK*NH) nb = NCHUNK*NH;
      coop_blocks = nb;
    }
  }

  hipError_t e = hipErrorUnknown;
  if (coop_blocks > 0){
    e = hipLaunchCooperativeKernel((const void*)k_fused,
        dim3(coop_blocks), dim3(320),
        (void**)(void*[]){ (void*)&x, (void*)&wm, (void*)&bm, (void*)&wa, (void*)&ba, (void*)&rot,
                           (void*)&Ku, (void*)&Qu, (void*)&Vu, (void*)&code, (void*)&hist, (void*)&spos,
                           (void*)&ret_u, (void*)&bs_u, (void*)&out },
        0, stream);
    if (e != hipSuccess) (void)hipGetLastError();   // clear sticky error
  }

  if (e != hipSuccess){
    // exact Round-0 baseline path
    hipMemsetAsync(hist, 0, (size_t)NH*NSEG*NBUCK*4, stream);
    hipLaunchKernelGGL(k_conv,   dim3(576),        dim3(256), 0, stream, x, wm, bm, wa, ba, rot, Ku, Qu, Vu, code, hist);
    hipLaunchKernelGGL(k_spos,   dim3(NSEG,NH),    dim3(256), 0, stream, code, hist, spos);
    hipLaunchKernelGGL(k_attn,   dim3(NCHUNK,NH),  dim3(320), 0, stream, Ku, Qu, Vu, spos, ret_u, bs_u);
    hipLaunchKernelGGL(k_final,  dim3(576),        dim3(256), 0, stream, x, ret_u, bs_u, out);
  }
}

// Round 3
// 127.668 us; speedup vs baseline: 2.8798x; 2.8611x over previous
//
#include <hip/hip_runtime.h>
#include <hip/hip_bf16.h>
#include <math.h>

#define LTOT 36864      // 192*192
#define NH 4
#define NCHUNK 256
#define CHU 144
#define NBUCK 128
#define NSEG 144        // 36864 / 256
#define HW_ 192
#define VTS 148         // VT row stride (u16)

typedef unsigned int u32;
typedef unsigned short u16;
typedef unsigned long long u64;
typedef __attribute__((ext_vector_type(4))) short short4v;
typedef __attribute__((ext_vector_type(4))) float f32x4;

__device__ __forceinline__ u32 pkbf(float a, float b){
  union { __hip_bfloat162 h2; u32 u; } cv;
  cv.h2 = __float22bfloat162_rn(float2{a,b});
  return cv.u;
}
__device__ __forceinline__ float bflo(u32 w){ return __uint_as_float(w<<16); }
__device__ __forceinline__ float bfhi(u32 w){ return __uint_as_float(w & 0xffff0000u); }

// ---------------- conv + hash + hist + bf16 K/Q/V pack (all unsorted): 576 blocks ----------------
// Wave w: 3x3 co-pair {2w,2w+1} + 1x1 co 8w..8w+7. Phase B: hash (px=lane,h=w);
// t<64 also packs Ku (normalized) / Qu (raw) bf16 rows from LDS xe rows.
__global__ __launch_bounds__(256) void k_conv(const float* __restrict__ x,
    const float* __restrict__ wm, const float* __restrict__ bm,
    const float* __restrict__ wa, const float* __restrict__ ba,
    const float* __restrict__ rot,
    u16* __restrict__ Ku, u16* __restrict__ Qu, u16* __restrict__ Vu,
    int* __restrict__ code, int* __restrict__ hist)
{
  __shared__ float xs[32*108];   // 32 ci x 6x18 halo
  __shared__ float xq[64*8];     // this tile's xe rows
  const int t = threadIdx.x;
  const int id = blockIdx.x;
  const int bx = id % 12, by = id / 12;

  for (int idx=t; idx<3456; idx+=256){
    int ci = idx/108, rem = idx-ci*108;
    int iy = rem/18,  ix = rem-iy*18;
    int yy = by*4+iy-1, xx = bx*16+ix-1;
    float v = 0.f;
    if (yy>=0 && yy<HW_ && xx>=0 && xx<HW_) v = x[ci*LTOT + yy*HW_ + xx];
    xs[idx] = v;
  }
  __syncthreads();
  const int lane = t & 63;
  const int w  = __builtin_amdgcn_readfirstlane(t>>6);
  const int co0 = 2*w, cb = 8*w;
  const int ix = lane & 15, iy = lane >> 4;
  float a0 = bm[co0], a1 = bm[co0+1];
  float acc[8];
  #pragma unroll
  for (int co=0;co<8;co++) acc[co] = ba[cb+co];
  const float* xb  = xs + iy*18 + ix;
  const float* w0p = wm + co0*288;
  const float* w1p = w0p + 288;
  for (int ci=0; ci<32; ci++){
    const float* xp = xb + ci*108;
    float x00=xp[0],  x01=xp[1],  x02=xp[2];
    float x10=xp[18], x11=xp[19], x12=xp[20];
    float x20=xp[36], x21=xp[37], x22=xp[38];
    const float* w0 = w0p + ci*9;
    const float* w1 = w1p + ci*9;
    a0 += x00*w0[0]+x01*w0[1]+x02*w0[2]
        + x10*w0[3]+x11*w0[4]+x12*w0[5]
        + x20*w0[6]+x21*w0[7]+x22*w0[8];
    a1 += x00*w1[0]+x01*w1[1]+x02*w1[2]
        + x10*w1[3]+x11*w1[4]+x12*w1[5]
        + x20*w1[6]+x21*w1[7]+x22*w1[8];
    const float* wap = wa + cb*32 + ci;
    #pragma unroll
    for (int co=0;co<8;co++) acc[co] += x11 * wap[co*32];
  }
  const int l = (by*4+iy)*HW_ + bx*16+ix;
  *(float2*)(xq + lane*8 + co0) = float2{a0,a1};
  uint4 vv;
  vv.x = pkbf(acc[0],acc[1]); vv.y = pkbf(acc[2],acc[3]);
  vv.z = pkbf(acc[4],acc[5]); vv.w = pkbf(acc[6],acc[7]);
  *(uint4*)(Vu + (size_t)l*32 + cb) = vv;
  __syncthreads();

  // pack Ku/Qu rows (t<64: one pixel each)
  if (t < 64){
    const int ly = t >> 4, lx = t & 15;
    const int lp = (by*4+ly)*HW_ + bx*16+lx;
    const float4* qp = (const float4*)(xq + t*8);
    float4 a = qp[0], b = qp[1];
    float n2 = a.x*a.x+a.y*a.y+a.z*a.z+a.w*a.w
             + b.x*b.x+b.y*b.y+b.z*b.z+b.w*b.w;
    float sc = 1.0f / fmaxf(sqrtf(n2), 5e-5f);
    uint4 kk, qq;
    kk.x = pkbf(a.x*sc,a.y*sc); kk.y = pkbf(a.z*sc,a.w*sc);
    kk.z = pkbf(b.x*sc,b.y*sc); kk.w = pkbf(b.z*sc,b.w*sc);
    qq.x = pkbf(a.x,a.y); qq.y = pkbf(a.z,a.w);
    qq.z = pkbf(b.x,b.y); qq.w = pkbf(b.z,b.w);
    *(uint4*)(Ku + (size_t)lp*8) = kk;
    *(uint4*)(Qu + (size_t)lp*8) = qq;
  }

  // hash: px = lane, h = wave id (wave-uniform rot access)
  {
    const int h = w;
    const float4* qp = (const float4*)(xq + lane*8);
    float4 qa = qp[0], qb = qp[1];
    float best = -INFINITY; int bi = 0;
    float worst = INFINITY; int wi = 0;
    for (int i=0; i<64; i++){
      const float* rp = rot + h*64 + i;   // rot[f*256 + h*64 + i]
      float v = qa.x*rp[0]    + qa.y*rp[256]  + qa.z*rp[512]  + qa.w*rp[768]
              + qb.x*rp[1024] + qb.y*rp[1280] + qb.z*rp[1536] + qb.w*rp[1792];
      if (v > best)  { best  = v; bi = i; }
      if (v < worst) { worst = v; wi = i; }
    }
    int c = (-worst > best) ? (64+wi) : bi;
    const int ly = lane >> 4, lx = lane & 15;
    const int lpix = (by*4+ly)*HW_ + bx*16+lx;
    code[h*LTOT + lpix] = c;
    atomicAdd(&hist[(h*NSEG + (lpix>>8))*NBUCK + c], 1);
  }
}

// ---------------- spos: per-block scan (from hist) + ballot rank ----------------
__global__ __launch_bounds__(256) void k_spos(const int* __restrict__ code,
    const int* __restrict__ hist, int* __restrict__ spos)
{
  const int h = blockIdx.y, seg = blockIdx.x, t = threadIdx.x;
  const int l = seg*256 + t;
  int c = code[h*LTOT + l];

  __shared__ int pre2[2][NBUCK], tot2[2][NBUCK];
  __shared__ int scv[NBUCK];
  __shared__ int segbase[NBUCK];
  __shared__ int wh[4][NBUCK];

  {
    const int b = t & 127, gg = t >> 7;
    int pre = 0, tt = 0;
    const int sA = gg*72;
    for (int s = sA; s < sA+72; s++){
      int v = hist[(h*NSEG+s)*NBUCK + b];
      tt += v;
      if (s < seg) pre += v;
    }
    pre2[gg][b] = pre; tot2[gg][b] = tt;
  }
  const int lane = t & 63, w = t >> 6;
  u64 mask = ~0ull;
  #pragma unroll
  for (int bit=0; bit<7; bit++){
    u64 bset = __ballot((c>>bit)&1);
    mask &= ((c>>bit)&1) ? bset : ~bset;
  }
  int rin = __popcll(mask & ((lane==0)?0ull:(~0ull >> (64-lane))));
  int cnt = __popcll(mask);
  ((int*)wh)[t] = 0; ((int*)wh)[t+256] = 0;
  __syncthreads();

  if (rin == 0) wh[w][c] = cnt;
  if (t < NBUCK){
    int tt = tot2[0][t] + tot2[1][t];
    int v = tt;
    #pragma unroll
    for (int off=1; off<64; off<<=1){
      int u = __shfl_up(v, off);
      if ((t & 63) >= off) v += u;
    }
    scv[t] = v;
  }
  __syncthreads();

  if (t < NBUCK){
    int tt = tot2[0][t] + tot2[1][t];
    int excl = scv[t] - tt + ((t >= 64) ? scv[63] : 0);
    segbase[t] = excl + pre2[0][t] + pre2[1][t];
  }
  __syncthreads();

  int r = segbase[c] + rin;
  for (int ww=0; ww<w; ww++) r += wh[ww][c];
  spos[h*LTOT + r] = l;
}

// ---------------- chunked attention: gather-staged via spos from shared unsorted Ku/Qu/Vu ----------------
// launch_bounds(320,5): cap VGPR at 102 so 4 blocks/CU fit (LDS 38.8KB allows it) -> 2x TLP.
__global__ __launch_bounds__(320, 5) void k_attn(const u16* __restrict__ Ku,
    const u16* __restrict__ Qu, const u16* __restrict__ Vu,
    const int* __restrict__ spos, u16* __restrict__ ret_u, float* __restrict__ bs_u)
{
  __shared__ __align__(16) u16 Klds[432*8];
  __shared__ __align__(16) u16 Qlds[CHU*8];
  __shared__ __align__(16) u16 VT[3][32*VTS];
  __shared__ float qn[CHU];
  __shared__ int spos_l[CHU];

  const int t = threadIdx.x;
  const int k = blockIdx.x, h = blockIdx.y;

  if (t < CHU){
    int pos0 = spos[h*LTOT + k*CHU + t];
    spos_l[t] = pos0;
    uint4 qv = *(const uint4*)(Qu + (size_t)pos0*8);
    *(uint4*)(Qlds + t*8) = qv;
    float f0=bflo(qv.x), f1=bfhi(qv.x), f2=bflo(qv.y), f3=bfhi(qv.y);
    float f4=bflo(qv.z), f5=bfhi(qv.z), f6=bflo(qv.w), f7=bfhi(qv.w);
    qn[t] = sqrtf(f0*f0+f1*f1+f2*f2+f3*f3+f4*f4+f5*f5+f6*f6+f7*f7)*1.01f + 1e-6f;
    #pragma unroll
    for (int rr=0; rr<3; rr++){
      const int gkb = ((k + NCHUNK-1 + rr) & (NCHUNK-1)) * CHU;
      int pk = spos[h*LTOT + gkb + t];
      *(uint4*)(Klds + (rr*CHU + t)*8) = *(const uint4*)(Ku + (size_t)pk*8);
    }
  }
  for (int j = t; j < 432; j += 320){
    int p = j >> 1, hf = j & 1;
    int g = 2*p;
    int rg = g / CHU, lk = g - rg*CHU;
    const int gkb = ((k + NCHUNK-1 + rg) & (NCHUNK-1)) * CHU;
    int posA = spos[h*LTOT + gkb + lk];
    int posB = spos[h*LTOT + gkb + lk + 1];
    const uint4* ra = (const uint4*)(Vu + (size_t)posA*32);
    const uint4* rb = (const uint4*)(Vu + (size_t)posB*32);
    uint4 A0 = ra[hf*2], A1 = ra[hf*2+1];
    uint4 B0 = rb[hf*2], B1 = rb[hf*2+1];
    u32 aw[8] = {A0.x,A0.y,A0.z,A0.w,A1.x,A1.y,A1.z,A1.w};
    u32 bw[8] = {B0.x,B0.y,B0.z,B0.w,B1.x,B1.y,B1.z,B1.w};
    int ebase = hf*16;
    u16* vtb = (u16*)VT[rg];
    #pragma unroll
    for (int m=0;m<8;m++){
      u32 al = aw[m]&0xffffu, ah = aw[m]>>16;
      u32 bl = bw[m]&0xffffu, bh = bw[m]>>16;
      *(u32*)&vtb[(ebase+2*m  )*VTS + lk] = al | (bl<<16);
      *(u32*)&vtb[(ebase+2*m+1)*VTS + lk] = ah | (bh<<16);
    }
  }
  __syncthreads();

  const int lane = t & 63;
  const int wv = t >> 6;                 // 0..4
  const int q = lane & 15;
  const int quad = lane >> 4;
  const bool two = (wv < 4);
  const int tl0 = 2*wv;
  const int tl1 = two ? (2*wv+1) : 8;

  const short4v zs = {0,0,0,0};
  short4v bq0 = zs, bq1 = zs;
  if (quad < 2){
    bq0 = *(const short4v*)(Qlds + (tl0*16+q)*8 + quad*4);
    if (two) bq1 = *(const short4v*)(Qlds + (tl1*16+q)*8 + quad*4);
  }
  const float m0 = qn[tl0*16+q];
  const float m1 = two ? qn[tl1*16+q] : 0.f;

  f32x4 o00={0,0,0,0}, o01={0,0,0,0}, o10={0,0,0,0}, o11={0,0,0,0};
  float s0 = 0.f, s1 = 0.f;

  #pragma unroll 3
  for (int kt=0; kt<27; kt++){
    const int rg = kt / 9, ktl = kt - rg*9;
    const u16* vtb = VT[rg];
    short4v av = zs;
    if (quad < 2) av = *(const short4v*)(Klds + (kt*16+q)*8 + quad*4);
    f32x4 zc = {0.f,0.f,0.f,0.f};
    f32x4 stA = __builtin_amdgcn_mfma_f32_16x16x16bf16_1k(av, bq0, zc, 0,0,0);

    float pA0 = __expf(stA[0]-m0), pA1 = __expf(stA[1]-m0);
    float pA2 = __expf(stA[2]-m0), pA3 = __expf(stA[3]-m0);
    s0 += (pA0+pA1)+(pA2+pA3);
    union { u32 u[2]; short4v s4; } pkA;
    pkA.u[0] = pkbf(pA0,pA1); pkA.u[1] = pkbf(pA2,pA3);

    short4v va0 = *(const short4v*)(&vtb[ q    *VTS + ktl*16 + quad*4]);
    short4v va1 = *(const short4v*)(&vtb[(q+16)*VTS + ktl*16 + quad*4]);
    o00 = __builtin_amdgcn_mfma_f32_16x16x16bf16_1k(va0, pkA.s4, o00, 0,0,0);
    o01 = __builtin_amdgcn_mfma_f32_16x16x16bf16_1k(va1, pkA.s4, o01, 0,0,0);

    if (two){
      f32x4 stB = __builtin_amdgcn_mfma_f32_16x16x16bf16_1k(av, bq1, zc, 0,0,0);
      float pB0 = __expf(stB[0]-m1), pB1 = __expf(stB[1]-m1);
      float pB2 = __expf(stB[2]-m1), pB3 = __expf(stB[3]-m1);
      s1 += (pB0+pB1)+(pB2+pB3);
      union { u32 u[2]; short4v s4; } pkB;
      pkB.u[0] = pkbf(pB0,pB1); pkB.u[1] = pkbf(pB2,pB3);
      o10 = __builtin_amdgcn_mfma_f32_16x16x16bf16_1k(va0, pkB.s4, o10, 0,0,0);
      o11 = __builtin_amdgcn_mfma_f32_16x16x16bf16_1k(va1, pkB.s4, o11, 0,0,0);
    }
  }

  float st0 = s0;
  st0 += __shfl_xor(st0, 16); st0 += __shfl_xor(st0, 32);
  float inv0 = 1.0f/st0;

  const int pos0 = spos_l[tl0*16 + q];
  u16* rp0 = ret_u + (size_t)(h*LTOT + pos0)*32;
  uint2 wA, wB;
  wA.x = pkbf(o00[0]*inv0, o00[1]*inv0); wA.y = pkbf(o00[2]*inv0, o00[3]*inv0);
  wB.x = pkbf(o01[0]*inv0, o01[1]*inv0); wB.y = pkbf(o01[2]*inv0, o01[3]*inv0);
  *(uint2*)&rp0[quad*4]    = wA;
  *(uint2*)&rp0[16+quad*4] = wB;
  if (quad == 0) bs_u[h*LTOT + pos0] = m0 + __logf(st0);

  if (two){
    float st1 = s1;
    st1 += __shfl_xor(st1, 16); st1 += __shfl_xor(st1, 32);
    float inv1 = 1.0f/st1;
    const int pos1 = spos_l[tl1*16 + q];
    u16* rp1 = ret_u + (size_t)(h*LTOT + pos1)*32;
    wA.x = pkbf(o10[0]*inv1, o10[1]*inv1); wA.y = pkbf(o10[2]*inv1, o10[3]*inv1);
    wB.x = pkbf(o11[0]*inv1, o11[1]*inv1); wB.y = pkbf(o11[2]*inv1, o11[3]*inv1);
    *(uint2*)&rp1[quad*4]    = wA;
    *(uint2*)&rp1[16+quad*4] = wB;
    if (quad == 0) bs_u[h*LTOT + pos1] = m1 + __logf(st1);
  }
}

// ---------------- cross-hash softmax + residual — fully coalesced ----------------
__global__ __launch_bounds__(256) void k_final(const float* __restrict__ x,
    const u16* __restrict__ ret_u, const float* __restrict__ bs_u,
    float* __restrict__ out)
{
  const int l  = blockIdx.x*64 + (threadIdx.x & 63);
  const int eg = threadIdx.x >> 6;
  float bs[NH];
  #pragma unroll
  for (int h=0;h<NH;h++) bs[h] = bs_u[h*LTOT + l];
  float m = fmaxf(fmaxf(bs[0],bs[1]), fmaxf(bs[2],bs[3]));
  float p[NH]; float s = 0.f;
  #pragma unroll
  for (int h=0;h<NH;h++){ p[h] = __expf(bs[h]-m); s += p[h]; }
  float inv = 1.0f/s;
  float o[8];
  #pragma unroll
  for (int e=0;e<8;e++) o[e]=0.f;
  #pragma unroll
  for (int h=0;h<NH;h++){
    float w = p[h]*inv;
    uint4 v = *(const uint4*)(ret_u + (size_t)(h*LTOT + l)*32 + eg*8);
    o[0] += w*bflo(v.x); o[1] += w*bfhi(v.x);
    o[2] += w*bflo(v.y); o[3] += w*bfhi(v.y);
    o[4] += w*bflo(v.z); o[5] += w*bfhi(v.z);
    o[6] += w*bflo(v.w); o[7] += w*bfhi(v.w);
  }
  #pragma unroll
  for (int e=0;e<8;e++){
    int ge = eg*8 + e;
    out[ge*LTOT + l] = o[e] + x[ge*LTOT + l];
  }
}

extern "C" void kernel_launch(void* const* d_in, const int* in_sizes, int n_in,
                              void* d_out, int out_size, void* d_ws, size_t ws_size,
                              hipStream_t stream)
{
  const float* x   = (const float*)d_in[0];
  const float* wm  = (const float*)d_in[1];
  const float* bm  = (const float*)d_in[2];
  const float* wa  = (const float*)d_in[3];
  const float* ba  = (const float*)d_in[4];
  const float* rot = (const float*)d_in[5];
  float* out = (float*)d_out;

  char* ws = (char*)d_ws;
  size_t off = 0;
  auto alloc = [&](size_t bytes)->void*{
    void* p = ws + off;
    off = (off + bytes + 255) & ~(size_t)255;
    return p;
  };
  u16*   Ku     = (u16*)  alloc((size_t)LTOT*8*2);
  u16*   Qu     = (u16*)  alloc((size_t)LTOT*8*2);
  u16*   Vu     = (u16*)  alloc((size_t)LTOT*32*2);
  int*   code   = (int*)  alloc((size_t)NH*LTOT*4);
  int*   hist   = (int*)  alloc((size_t)NH*NSEG*NBUCK*4);
  int*   spos   = (int*)  alloc((size_t)NH*LTOT*4);
  u16*   ret_u  = (u16*)  alloc((size_t)NH*LTOT*32*2);
  float* bs_u   = (float*)alloc((size_t)NH*LTOT*4);

  hipMemsetAsync(hist, 0, (size_t)NH*NSEG*NBUCK*4, stream);
  hipLaunchKernelGGL(k_conv,   dim3(576),        dim3(256), 0, stream, x, wm, bm, wa, ba, rot, Ku, Qu, Vu, code, hist);
  hipLaunchKernelGGL(k_spos,   dim3(NSEG,NH),    dim3(256), 0, stream, code, hist, spos);
  hipLaunchKernelGGL(k_attn,   dim3(NCHUNK,NH),  dim3(320), 0, stream, Ku, Qu, Vu, spos, ret_u, bs_u);
  hipLaunchKernelGGL(k_final,  dim3(576),        dim3(256), 0, stream, x, ret_u, bs_u, out);
}

// Round 4
// 125.475 us; speedup vs baseline: 2.9301x; 1.0175x over previous
//
#include <hip/hip_runtime.h>
#include <hip/hip_bf16.h>
#include <math.h>

#define LTOT 36864      // 192*192
#define NH 4
#define NCHUNK 256
#define CHU 144
#define NBUCK 128
#define NSEG 144        // 36864 / 256
#define HW_ 192
#define VTS 148         // VT row stride (u16)
#define LOG2E 1.44269504088896340736f

// native exp2/log2 (v_exp_f32 computes 2^x, v_log_f32 computes log2(x))
#if defined(__has_builtin)
#  if __has_builtin(__builtin_amdgcn_exp2f)
#    define EXP2(x) __builtin_amdgcn_exp2f(x)
#  else
#    define EXP2(x) exp2f(x)
#  endif
#  if __has_builtin(__builtin_amdgcn_logf)
#    define LOG2(x) __builtin_amdgcn_logf(x)
#  else
#    define LOG2(x) log2f(x)
#  endif
#else
#  define EXP2(x) exp2f(x)
#  define LOG2(x) log2f(x)
#endif

typedef unsigned int u32;
typedef unsigned short u16;
typedef unsigned long long u64;
typedef __attribute__((ext_vector_type(4))) short short4v;
typedef __attribute__((ext_vector_type(4))) float f32x4;

__device__ __forceinline__ u32 pkbf(float a, float b){
  union { __hip_bfloat162 h2; u32 u; } cv;
  cv.h2 = __float22bfloat162_rn(float2{a,b});
  return cv.u;
}
__device__ __forceinline__ float bflo(u32 w){ return __uint_as_float(w<<16); }
__device__ __forceinline__ float bfhi(u32 w){ return __uint_as_float(w & 0xffff0000u); }

// ---------------- conv + hash + hist + bf16 K/Q/V pack (all unsorted): 576 blocks ----------------
// Qu is pre-scaled by log2(e): downstream softmax runs in exp2-domain (exact algebra).
__global__ __launch_bounds__(256) void k_conv(const float* __restrict__ x,
    const float* __restrict__ wm, const float* __restrict__ bm,
    const float* __restrict__ wa, const float* __restrict__ ba,
    const float* __restrict__ rot,
    u16* __restrict__ Ku, u16* __restrict__ Qu, u16* __restrict__ Vu,
    int* __restrict__ code, int* __restrict__ hist)
{
  __shared__ float xs[32*108];   // 32 ci x 6x18 halo
  __shared__ float xq[64*8];     // this tile's xe rows
  __shared__ float rotS[2048];   // full rotations tensor (8*4*64 f32)
  const int t = threadIdx.x;
  const int id = blockIdx.x;
  const int bx = id % 12, by = id / 12;

  for (int idx=t; idx<3456; idx+=256){
    int ci = idx/108, rem = idx-ci*108;
    int iy = rem/18,  ix = rem-iy*18;
    int yy = by*4+iy-1, xx = bx*16+ix-1;
    float v = 0.f;
    if (yy>=0 && yy<HW_ && xx>=0 && xx<HW_) v = x[ci*LTOT + yy*HW_ + xx];
    xs[idx] = v;
  }
  for (int idx=t; idx<2048; idx+=256) rotS[idx] = rot[idx];
  __syncthreads();
  const int lane = t & 63;
  const int w  = __builtin_amdgcn_readfirstlane(t>>6);
  const int co0 = 2*w, cb = 8*w;
  const int ix = lane & 15, iy = lane >> 4;
  float a0 = bm[co0], a1 = bm[co0+1];
  float acc[8];
  #pragma unroll
  for (int co=0;co<8;co++) acc[co] = ba[cb+co];
  const float* xb  = xs + iy*18 + ix;
  const float* w0p = wm + co0*288;
  const float* w1p = w0p + 288;
  for (int ci=0; ci<32; ci++){
    const float* xp = xb + ci*108;
    float x00=xp[0],  x01=xp[1],  x02=xp[2];
    float x10=xp[18], x11=xp[19], x12=xp[20];
    float x20=xp[36], x21=xp[37], x22=xp[38];
    const float* w0 = w0p + ci*9;
    const float* w1 = w1p + ci*9;
    a0 += x00*w0[0]+x01*w0[1]+x02*w0[2]
        + x10*w0[3]+x11*w0[4]+x12*w0[5]
        + x20*w0[6]+x21*w0[7]+x22*w0[8];
    a1 += x00*w1[0]+x01*w1[1]+x02*w1[2]
        + x10*w1[3]+x11*w1[4]+x12*w1[5]
        + x20*w1[6]+x21*w1[7]+x22*w1[8];
    const float* wap = wa + cb*32 + ci;
    #pragma unroll
    for (int co=0;co<8;co++) acc[co] += x11 * wap[co*32];
  }
  const int l = (by*4+iy)*HW_ + bx*16+ix;
  *(float2*)(xq + lane*8 + co0) = float2{a0,a1};
  uint4 vv;
  vv.x = pkbf(acc[0],acc[1]); vv.y = pkbf(acc[2],acc[3]);
  vv.z = pkbf(acc[4],acc[5]); vv.w = pkbf(acc[6],acc[7]);
  *(uint4*)(Vu + (size_t)l*32 + cb) = vv;
  __syncthreads();

  // pack Ku/Qu rows (t<64: one pixel each). Qu scaled by log2(e).
  if (t < 64){
    const int ly = t >> 4, lx = t & 15;
    const int lp = (by*4+ly)*HW_ + bx*16+lx;
    const float4* qp = (const float4*)(xq + t*8);
    float4 a = qp[0], b = qp[1];
    float n2 = a.x*a.x+a.y*a.y+a.z*a.z+a.w*a.w
             + b.x*b.x+b.y*b.y+b.z*b.z+b.w*b.w;
    float sc = 1.0f / fmaxf(sqrtf(n2), 5e-5f);
    uint4 kk, qq;
    kk.x = pkbf(a.x*sc,a.y*sc); kk.y = pkbf(a.z*sc,a.w*sc);
    kk.z = pkbf(b.x*sc,b.y*sc); kk.w = pkbf(b.z*sc,b.w*sc);
    qq.x = pkbf(a.x*LOG2E,a.y*LOG2E); qq.y = pkbf(a.z*LOG2E,a.w*LOG2E);
    qq.z = pkbf(b.x*LOG2E,b.y*LOG2E); qq.w = pkbf(b.z*LOG2E,b.w*LOG2E);
    *(uint4*)(Ku + (size_t)lp*8) = kk;
    *(uint4*)(Qu + (size_t)lp*8) = qq;
  }

  // hash: px = lane, h = wave id; rot read from LDS (uniform-address broadcast)
  {
    const int h = w;
    const float4* qp = (const float4*)(xq + lane*8);
    float4 qa = qp[0], qb = qp[1];
    float best = -INFINITY; int bi = 0;
    float worst = INFINITY; int wi = 0;
    for (int i=0; i<64; i++){
      const float* rp = rotS + h*64 + i;   // rot[f*256 + h*64 + i]
      float v = qa.x*rp[0]    + qa.y*rp[256]  + qa.z*rp[512]  + qa.w*rp[768]
              + qb.x*rp[1024] + qb.y*rp[1280] + qb.z*rp[1536] + qb.w*rp[1792];
      if (v > best)  { best  = v; bi = i; }
      if (v < worst) { worst = v; wi = i; }
    }
    int c = (-worst > best) ? (64+wi) : bi;
    const int ly = lane >> 4, lx = lane & 15;
    const int lpix = (by*4+ly)*HW_ + bx*16+lx;
    code[h*LTOT + lpix] = c;
    atomicAdd(&hist[(h*NSEG + (lpix>>8))*NBUCK + c], 1);
  }
}

// ---------------- spos: per-block scan (from hist) + ballot rank ----------------
__global__ __launch_bounds__(256) void k_spos(const int* __restrict__ code,
    const int* __restrict__ hist, int* __restrict__ spos)
{
  const int h = blockIdx.y, seg = blockIdx.x, t = threadIdx.x;
  const int l = seg*256 + t;
  int c = code[h*LTOT + l];

  __shared__ int pre2[2][NBUCK], tot2[2][NBUCK];
  __shared__ int scv[NBUCK];
  __shared__ int segbase[NBUCK];
  __shared__ int wh[4][NBUCK];

  {
    const int b = t & 127, gg = t >> 7;
    int pre = 0, tt = 0;
    const int sA = gg*72;
    #pragma unroll 4
    for (int s = sA; s < sA+72; s++){
      int v = hist[(h*NSEG+s)*NBUCK + b];
      tt += v;
      if (s < seg) pre += v;
    }
    pre2[gg][b] = pre; tot2[gg][b] = tt;
  }
  const int lane = t & 63, w = t >> 6;
  u64 mask = ~0ull;
  #pragma unroll
  for (int bit=0; bit<7; bit++){
    u64 bset = __ballot((c>>bit)&1);
    mask &= ((c>>bit)&1) ? bset : ~bset;
  }
  int rin = __popcll(mask & ((lane==0)?0ull:(~0ull >> (64-lane))));
  int cnt = __popcll(mask);
  ((int*)wh)[t] = 0; ((int*)wh)[t+256] = 0;
  __syncthreads();

  if (rin == 0) wh[w][c] = cnt;
  if (t < NBUCK){
    int tt = tot2[0][t] + tot2[1][t];
    int v = tt;
    #pragma unroll
    for (int off=1; off<64; off<<=1){
      int u = __shfl_up(v, off);
      if ((t & 63) >= off) v += u;
    }
    scv[t] = v;
  }
  __syncthreads();

  if (t < NBUCK){
    int tt = tot2[0][t] + tot2[1][t];
    int excl = scv[t] - tt + ((t >= 64) ? scv[63] : 0);
    segbase[t] = excl + pre2[0][t] + pre2[1][t];
  }
  __syncthreads();

  int r = segbase[c] + rin;
  for (int ww=0; ww<w; ww++) r += wh[ww][c];
  spos[h*LTOT + r] = l;
}

// ---------------- chunked attention: exp2-domain softmax (Qu pre-scaled by log2 e) ----------------
__global__ __launch_bounds__(320, 5) void k_attn(const u16* __restrict__ Ku,
    const u16* __restrict__ Qu, const u16* __restrict__ Vu,
    const int* __restrict__ spos, u16* __restrict__ ret_u, float* __restrict__ bs_u)
{
  __shared__ __align__(16) u16 Klds[432*8];
  __shared__ __align__(16) u16 Qlds[CHU*8];
  __shared__ __align__(16) u16 VT[3][32*VTS];
  __shared__ float qn[CHU];
  __shared__ int spos_l[CHU];

  const int t = threadIdx.x;
  const int k = blockIdx.x, h = blockIdx.y;

  if (t < CHU){
    int pos0 = spos[h*LTOT + k*CHU + t];
    spos_l[t] = pos0;
    uint4 qv = *(const uint4*)(Qu + (size_t)pos0*8);
    *(uint4*)(Qlds + t*8) = qv;
    float f0=bflo(qv.x), f1=bfhi(qv.x), f2=bflo(qv.y), f3=bfhi(qv.y);
    float f4=bflo(qv.z), f5=bfhi(qv.z), f6=bflo(qv.w), f7=bfhi(qv.w);
    // qn computed from the lambda-scaled Qu values -> lambda-scaled max bound (exact algebra)
    qn[t] = sqrtf(f0*f0+f1*f1+f2*f2+f3*f3+f4*f4+f5*f5+f6*f6+f7*f7)*1.01f + 1e-6f;
    #pragma unroll
    for (int rr=0; rr<3; rr++){
      const int gkb = ((k + NCHUNK-1 + rr) & (NCHUNK-1)) * CHU;
      int pk = spos[h*LTOT + gkb + t];
      *(uint4*)(Klds + (rr*CHU + t)*8) = *(const uint4*)(Ku + (size_t)pk*8);
    }
  }
  for (int j = t; j < 432; j += 320){
    int p = j >> 1, hf = j & 1;
    int g = 2*p;
    int rg = g / CHU, lk = g - rg*CHU;
    const int gkb = ((k + NCHUNK-1 + rg) & (NCHUNK-1)) * CHU;
    int posA = spos[h*LTOT + gkb + lk];
    int posB = spos[h*LTOT + gkb + lk + 1];
    const uint4* ra = (const uint4*)(Vu + (size_t)posA*32);
    const uint4* rb = (const uint4*)(Vu + (size_t)posB*32);
    uint4 A0 = ra[hf*2], A1 = ra[hf*2+1];
    uint4 B0 = rb[hf*2], B1 = rb[hf*2+1];
    u32 aw[8] = {A0.x,A0.y,A0.z,A0.w,A1.x,A1.y,A1.z,A1.w};
    u32 bw[8] = {B0.x,B0.y,B0.z,B0.w,B1.x,B1.y,B1.z,B1.w};
    int ebase = hf*16;
    u16* vtb = (u16*)VT[rg];
    #pragma unroll
    for (int m=0;m<8;m++){
      u32 al = aw[m]&0xffffu, ah = aw[m]>>16;
      u32 bl = bw[m]&0xffffu, bh = bw[m]>>16;
      *(u32*)&vtb[(ebase+2*m  )*VTS + lk] = al | (bl<<16);
      *(u32*)&vtb[(ebase+2*m+1)*VTS + lk] = ah | (bh<<16);
    }
  }
  __syncthreads();

  const int lane = t & 63;
  const int wv = t >> 6;                 // 0..4
  const int q = lane & 15;
  const int quad = lane >> 4;
  const bool two = (wv < 4);
  const int tl0 = 2*wv;
  const int tl1 = two ? (2*wv+1) : 8;

  const short4v zs = {0,0,0,0};
  short4v bq0 = zs, bq1 = zs;
  if (quad < 2){
    bq0 = *(const short4v*)(Qlds + (tl0*16+q)*8 + quad*4);
    if (two) bq1 = *(const short4v*)(Qlds + (tl1*16+q)*8 + quad*4);
  }
  const float m0 = qn[tl0*16+q];
  const float m1 = two ? qn[tl1*16+q] : 0.f;

  f32x4 o00={0,0,0,0}, o01={0,0,0,0}, o10={0,0,0,0}, o11={0,0,0,0};
  float s0 = 0.f, s1 = 0.f;

  #pragma unroll 3
  for (int kt=0; kt<27; kt++){
    const int rg = kt / 9, ktl = kt - rg*9;
    const u16* vtb = VT[rg];
    short4v av = zs;
    if (quad < 2) av = *(const short4v*)(Klds + (kt*16+q)*8 + quad*4);
    f32x4 zc = {0.f,0.f,0.f,0.f};
    f32x4 stA = __builtin_amdgcn_mfma_f32_16x16x16bf16_1k(av, bq0, zc, 0,0,0);

    float pA0 = EXP2(stA[0]-m0), pA1 = EXP2(stA[1]-m0);
    float pA2 = EXP2(stA[2]-m0), pA3 = EXP2(stA[3]-m0);
    s0 += (pA0+pA1)+(pA2+pA3);
    union { u32 u[2]; short4v s4; } pkA;
    pkA.u[0] = pkbf(pA0,pA1); pkA.u[1] = pkbf(pA2,pA3);

    short4v va0 = *(const short4v*)(&vtb[ q    *VTS + ktl*16 + quad*4]);
    short4v va1 = *(const short4v*)(&vtb[(q+16)*VTS + ktl*16 + quad*4]);
    o00 = __builtin_amdgcn_mfma_f32_16x16x16bf16_1k(va0, pkA.s4, o00, 0,0,0);
    o01 = __builtin_amdgcn_mfma_f32_16x16x16bf16_1k(va1, pkA.s4, o01, 0,0,0);

    if (two){
      f32x4 stB = __builtin_amdgcn_mfma_f32_16x16x16bf16_1k(av, bq1, zc, 0,0,0);
      float pB0 = EXP2(stB[0]-m1), pB1 = EXP2(stB[1]-m1);
      float pB2 = EXP2(stB[2]-m1), pB3 = EXP2(stB[3]-m1);
      s1 += (pB0+pB1)+(pB2+pB3);
      union { u32 u[2]; short4v s4; } pkB;
      pkB.u[0] = pkbf(pB0,pB1); pkB.u[1] = pkbf(pB2,pB3);
      o10 = __builtin_amdgcn_mfma_f32_16x16x16bf16_1k(va0, pkB.s4, o10, 0,0,0);
      o11 = __builtin_amdgcn_mfma_f32_16x16x16bf16_1k(va1, pkB.s4, o11, 0,0,0);
    }
  }

  float st0 = s0;
  st0 += __shfl_xor(st0, 16); st0 += __shfl_xor(st0, 32);
  float inv0 = 1.0f/st0;

  const int pos0 = spos_l[tl0*16 + q];
  u16* rp0 = ret_u + (size_t)(h*LTOT + pos0)*32;
  uint2 wA, wB;
  wA.x = pkbf(o00[0]*inv0, o00[1]*inv0); wA.y = pkbf(o00[2]*inv0, o00[3]*inv0);
  wB.x = pkbf(o01[0]*inv0, o01[1]*inv0); wB.y = pkbf(o01[2]*inv0, o01[3]*inv0);
  *(uint2*)&rp0[quad*4]    = wA;
  *(uint2*)&rp0[16+quad*4] = wB;
  if (quad == 0) bs_u[h*LTOT + pos0] = m0 + LOG2(st0);   // log2-domain bucket score (= lambda * ln-domain)

  if (two){
    float st1 = s1;
    st1 += __shfl_xor(st1, 16); st1 += __shfl_xor(st1, 32);
    float inv1 = 1.0f/st1;
    const int pos1 = spos_l[tl1*16 + q];
    u16* rp1 = ret_u + (size_t)(h*LTOT + pos1)*32;
    wA.x = pkbf(o10[0]*inv1, o10[1]*inv1); wA.y = pkbf(o10[2]*inv1, o10[3]*inv1);
    wB.x = pkbf(o11[0]*inv1, o11[1]*inv1); wB.y = pkbf(o11[2]*inv1, o11[3]*inv1);
    *(uint2*)&rp1[quad*4]    = wA;
    *(uint2*)&rp1[16+quad*4] = wB;
    if (quad == 0) bs_u[h*LTOT + pos1] = m1 + LOG2(st1);
  }
}

// ---------------- cross-hash softmax + residual — exp2-domain (exact: 2^(lambda*d) = e^d) ----------------
__global__ __launch_bounds__(256) void k_final(const float* __restrict__ x,
    const u16* __restrict__ ret_u, const float* __restrict__ bs_u,
    float* __restrict__ out)
{
  const int l  = blockIdx.x*64 + (threadIdx.x & 63);
  const int eg = threadIdx.x >> 6;
  float bs[NH];
  #pragma unroll
  for (int h=0;h<NH;h++) bs[h] = bs_u[h*LTOT + l];
  float m = fmaxf(fmaxf(bs[0],bs[1]), fmaxf(bs[2],bs[3]));
  float p[NH]; float s = 0.f;
  #pragma unroll
  for (int h=0;h<NH;h++){ p[h] = EXP2(bs[h]-m); s += p[h]; }
  float inv = 1.0f/s;
  float o[8];
  #pragma unroll
  for (int e=0;e<8;e++) o[e]=0.f;
  #pragma unroll
  for (int h=0;h<NH;h++){
    float w = p[h]*inv;
    uint4 v = *(const uint4*)(ret_u + (size_t)(h*LTOT + l)*32 + eg*8);
    o[0] += w*bflo(v.x); o[1] += w*bfhi(v.x);
    o[2] += w*bflo(v.y); o[3] += w*bfhi(v.y);
    o[4] += w*bflo(v.z); o[5] += w*bfhi(v.z);
    o[6] += w*bflo(v.w); o[7] += w*bfhi(v.w);
  }
  #pragma unroll
  for (int e=0;e<8;e++){
    int ge = eg*8 + e;
    out[ge*LTOT + l] = o[e] + x[ge*LTOT + l];
  }
}

extern "C" void kernel_launch(void* const* d_in, const int* in_sizes, int n_in,
                              void* d_out, int out_size, void* d_ws, size_t ws_size,
                              hipStream_t stream)
{
  const float* x   = (const float*)d_in[0];
  const float* wm  = (const float*)d_in[1];
  const float* bm  = (const float*)d_in[2];
  const float* wa  = (const float*)d_in[3];
  const float* ba  = (const float*)d_in[4];
  const float* rot = (const float*)d_in[5];
  float* out = (float*)d_out;

  char* ws = (char*)d_ws;
  size_t off = 0;
  auto alloc = [&](size_t bytes)->void*{
    void* p = ws + off;
    off = (off + bytes + 255) & ~(size_t)255;
    return p;
  };
  u16*   Ku     = (u16*)  alloc((size_t)LTOT*8*2);
  u16*   Qu     = (u16*)  alloc((size_t)LTOT*8*2);
  u16*   Vu     = (u16*)  alloc((size_t)LTOT*32*2);
  int*   code   = (int*)  alloc((size_t)NH*LTOT*4);
  int*   hist   = (int*)  alloc((size_t)NH*NSEG*NBUCK*4);
  int*   spos   = (int*)  alloc((size_t)NH*LTOT*4);
  u16*   ret_u  = (u16*)  alloc((size_t)NH*LTOT*32*2);
  float* bs_u   = (float*)alloc((size_t)NH*LTOT*4);

  hipMemsetAsync(hist, 0, (size_t)NH*NSEG*NBUCK*4, stream);
  hipLaunchKernelGGL(k_conv,   dim3(576),        dim3(256), 0, stream, x, wm, bm, wa, ba, rot, Ku, Qu, Vu, code, hist);
  hipLaunchKernelGGL(k_spos,   dim3(NSEG,NH),    dim3(256), 0, stream, code, hist, spos);
  hipLaunchKernelGGL(k_attn,   dim3(NCHUNK,NH),  dim3(320), 0, stream, Ku, Qu, Vu, spos, ret_u, bs_u);
  hipLaunchKernelGGL(k_final,  dim3(576),        dim3(256), 0, stream, x, ret_u, bs_u, out);
}

// Round 5
// 122.564 us; speedup vs baseline: 2.9997x; 1.0238x over previous
//
#include <hip/hip_runtime.h>
#include <hip/hip_bf16.h>
#include <math.h>

#define LTOT 36864      // 192*192
#define NH 4
#define NCHUNK 256
#define CHU 144
#define NBUCK 128
#define NSEG 144        // 36864 / 256
#define HW_ 192
#define VTS 148         // VT row stride (u16)
#define LOG2E 1.44269504088896340736f

// native exp2/log2 (v_exp_f32 computes 2^x, v_log_f32 computes log2(x))
#if defined(__has_builtin)
#  if __has_builtin(__builtin_amdgcn_exp2f)
#    define EXP2(x) __builtin_amdgcn_exp2f(x)
#  else
#    define EXP2(x) exp2f(x)
#  endif
#  if __has_builtin(__builtin_amdgcn_logf)
#    define LOG2(x) __builtin_amdgcn_logf(x)
#  else
#    define LOG2(x) log2f(x)
#  endif
#else
#  define EXP2(x) exp2f(x)
#  define LOG2(x) log2f(x)
#endif

typedef unsigned int u32;
typedef unsigned short u16;
typedef unsigned long long u64;
typedef __attribute__((ext_vector_type(4))) short short4v;
typedef __attribute__((ext_vector_type(4))) float f32x4;

__device__ __forceinline__ u32 pkbf(float a, float b){
  union { __hip_bfloat162 h2; u32 u; } cv;
  cv.h2 = __float22bfloat162_rn(float2{a,b});
  return cv.u;
}
__device__ __forceinline__ float bflo(u32 w){ return __uint_as_float(w<<16); }
__device__ __forceinline__ float bfhi(u32 w){ return __uint_as_float(w & 0xffff0000u); }

// ---------------- conv + hash + hist + bf16 K/Q/V pack (all unsorted): 576 blocks ----------------
// Qu is pre-scaled by log2(e): downstream softmax runs in exp2-domain (exact algebra).
// rot staged TRANSPOSED in LDS: rotT[h][i][f] -> hash loop reads 2x b128 broadcast per i.
__global__ __launch_bounds__(256) void k_conv(const float* __restrict__ x,
    const float* __restrict__ wm, const float* __restrict__ bm,
    const float* __restrict__ wa, const float* __restrict__ ba,
    const float* __restrict__ rot,
    u16* __restrict__ Ku, u16* __restrict__ Qu, u16* __restrict__ Vu,
    int* __restrict__ code, int* __restrict__ hist)
{
  __shared__ float xs[32*108];   // 32 ci x 6x18 halo
  __shared__ float xq[64*8];     // this tile's xe rows
  __shared__ __align__(16) float rotT[2048];   // transposed: [h][i][f] (8 f32 contiguous per (h,i))
  const int t = threadIdx.x;
  const int id = blockIdx.x;
  const int bx = id % 12, by = id / 12;

  for (int idx=t; idx<3456; idx+=256){
    int ci = idx/108, rem = idx-ci*108;
    int iy = rem/18,  ix = rem-iy*18;
    int yy = by*4+iy-1, xx = bx*16+ix-1;
    float v = 0.f;
    if (yy>=0 && yy<HW_ && xx>=0 && xx<HW_) v = x[ci*LTOT + yy*HW_ + xx];
    xs[idx] = v;
  }
  // stage rot transposed: src rot[f*256 + h*64 + i] -> rotT[h*512 + i*8 + f]
  for (int s=t; s<2048; s+=256){
    int f = s >> 8, rem = s & 255;
    int hh = rem >> 6, ii = rem & 63;
    rotT[hh*512 + ii*8 + f] = rot[s];
  }
  __syncthreads();
  const int lane = t & 63;
  const int w  = __builtin_amdgcn_readfirstlane(t>>6);
  const int co0 = 2*w, cb = 8*w;
  const int ix = lane & 15, iy = lane >> 4;
  float a0 = bm[co0], a1 = bm[co0+1];
  float acc[8];
  #pragma unroll
  for (int co=0;co<8;co++) acc[co] = ba[cb+co];
  const float* xb  = xs + iy*18 + ix;
  const float* w0p = wm + co0*288;
  const float* w1p = w0p + 288;
  for (int ci=0; ci<32; ci++){
    const float* xp = xb + ci*108;
    float x00=xp[0],  x01=xp[1],  x02=xp[2];
    float x10=xp[18], x11=xp[19], x12=xp[20];
    float x20=xp[36], x21=xp[37], x22=xp[38];
    const float* w0 = w0p + ci*9;
    const float* w1 = w1p + ci*9;
    a0 += x00*w0[0]+x01*w0[1]+x02*w0[2]
        + x10*w0[3]+x11*w0[4]+x12*w0[5]
        + x20*w0[6]+x21*w0[7]+x22*w0[8];
    a1 += x00*w1[0]+x01*w1[1]+x02*w1[2]
        + x10*w1[3]+x11*w1[4]+x12*w1[5]
        + x20*w1[6]+x21*w1[7]+x22*w1[8];
    const float* wap = wa + cb*32 + ci;
    #pragma unroll
    for (int co=0;co<8;co++) acc[co] += x11 * wap[co*32];
  }
  const int l = (by*4+iy)*HW_ + bx*16+ix;
  *(float2*)(xq + lane*8 + co0) = float2{a0,a1};
  uint4 vv;
  vv.x = pkbf(acc[0],acc[1]); vv.y = pkbf(acc[2],acc[3]);
  vv.z = pkbf(acc[4],acc[5]); vv.w = pkbf(acc[6],acc[7]);
  *(uint4*)(Vu + (size_t)l*32 + cb) = vv;
  __syncthreads();

  // pack Ku/Qu rows (t<64: one pixel each). Qu scaled by log2(e).
  if (t < 64){
    const int ly = t >> 4, lx = t & 15;
    const int lp = (by*4+ly)*HW_ + bx*16+lx;
    const float4* qp = (const float4*)(xq + t*8);
    float4 a = qp[0], b = qp[1];
    float n2 = a.x*a.x+a.y*a.y+a.z*a.z+a.w*a.w
             + b.x*b.x+b.y*b.y+b.z*b.z+b.w*b.w;
    float sc = 1.0f / fmaxf(sqrtf(n2), 5e-5f);
    uint4 kk, qq;
    kk.x = pkbf(a.x*sc,a.y*sc); kk.y = pkbf(a.z*sc,a.w*sc);
    kk.z = pkbf(b.x*sc,b.y*sc); kk.w = pkbf(b.z*sc,b.w*sc);
    qq.x = pkbf(a.x*LOG2E,a.y*LOG2E); qq.y = pkbf(a.z*LOG2E,a.w*LOG2E);
    qq.z = pkbf(b.x*LOG2E,b.y*LOG2E); qq.w = pkbf(b.z*LOG2E,b.w*LOG2E);
    *(uint4*)(Ku + (size_t)lp*8) = kk;
    *(uint4*)(Qu + (size_t)lp*8) = qq;
  }

  // hash: px = lane, h = wave id; rotT read as 2x float4 broadcast per i
  {
    const int h = w;
    const float4* qp = (const float4*)(xq + lane*8);
    float4 qa = qp[0], qb = qp[1];
    const float* rb = rotT + h*512;
    float best = -INFINITY; int bi = 0;
    float worst = INFINITY; int wi = 0;
    for (int i=0; i<64; i++){
      const float4* rp4 = (const float4*)(rb + i*8);
      float4 r0 = rp4[0], r1 = rp4[1];
      float v = qa.x*r0.x + qa.y*r0.y + qa.z*r0.z + qa.w*r0.w
              + qb.x*r1.x + qb.y*r1.y + qb.z*r1.z + qb.w*r1.w;
      if (v > best)  { best  = v; bi = i; }
      if (v < worst) { worst = v; wi = i; }
    }
    int c = (-worst > best) ? (64+wi) : bi;
    const int ly = lane >> 4, lx = lane & 15;
    const int lpix = (by*4+ly)*HW_ + bx*16+lx;
    code[h*LTOT + lpix] = c;
    atomicAdd(&hist[(h*NSEG + (lpix>>8))*NBUCK + c], 1);
  }
}

// ---------------- spos: per-block scan (from hist) + ballot rank ----------------
__global__ __launch_bounds__(256) void k_spos(const int* __restrict__ code,
    const int* __restrict__ hist, int* __restrict__ spos)
{
  const int h = blockIdx.y, seg = blockIdx.x, t = threadIdx.x;
  const int l = seg*256 + t;
  int c = code[h*LTOT + l];

  __shared__ int pre2[2][NBUCK], tot2[2][NBUCK];
  __shared__ int scv[NBUCK];
  __shared__ int segbase[NBUCK];
  __shared__ int wh[4][NBUCK];

  {
    const int b = t & 127, gg = t >> 7;
    int pre = 0, tt = 0;
    const int sA = gg*72;
    #pragma unroll 4
    for (int s = sA; s < sA+72; s++){
      int v = hist[(h*NSEG+s)*NBUCK + b];
      tt += v;
      if (s < seg) pre += v;
    }
    pre2[gg][b] = pre; tot2[gg][b] = tt;
  }
  const int lane = t & 63, w = t >> 6;
  u64 mask = ~0ull;
  #pragma unroll
  for (int bit=0; bit<7; bit++){
    u64 bset = __ballot((c>>bit)&1);
    mask &= ((c>>bit)&1) ? bset : ~bset;
  }
  int rin = __popcll(mask & ((lane==0)?0ull:(~0ull >> (64-lane))));
  int cnt = __popcll(mask);
  ((int*)wh)[t] = 0; ((int*)wh)[t+256] = 0;
  __syncthreads();

  if (rin == 0) wh[w][c] = cnt;
  if (t < NBUCK){
    int tt = tot2[0][t] + tot2[1][t];
    int v = tt;
    #pragma unroll
    for (int off=1; off<64; off<<=1){
      int u = __shfl_up(v, off);
      if ((t & 63) >= off) v += u;
    }
    scv[t] = v;
  }
  __syncthreads();

  if (t < NBUCK){
    int tt = tot2[0][t] + tot2[1][t];
    int excl = scv[t] - tt + ((t >= 64) ? scv[63] : 0);
    segbase[t] = excl + pre2[0][t] + pre2[1][t];
  }
  __syncthreads();

  int r = segbase[c] + rin;
  for (int ww=0; ww<w; ww++) r += wh[ww][c];
  spos[h*LTOT + r] = l;
}

// ---------------- chunked attention: exp2-domain softmax; -m folded into MFMA C ----------------
__global__ __launch_bounds__(320, 5) void k_attn(const u16* __restrict__ Ku,
    const u16* __restrict__ Qu, const u16* __restrict__ Vu,
    const int* __restrict__ spos, u16* __restrict__ ret_u, float* __restrict__ bs_u)
{
  __shared__ __align__(16) u16 Klds[432*8];
  __shared__ __align__(16) u16 Qlds[CHU*8];
  __shared__ __align__(16) u16 VT[3][32*VTS];
  __shared__ float qn[CHU];
  __shared__ int spos_l[CHU];

  const int t = threadIdx.x;
  const int k = blockIdx.x, h = blockIdx.y;

  if (t < CHU){
    int pos0 = spos[h*LTOT + k*CHU + t];
    spos_l[t] = pos0;
    uint4 qv = *(const uint4*)(Qu + (size_t)pos0*8);
    *(uint4*)(Qlds + t*8) = qv;
    float f0=bflo(qv.x), f1=bfhi(qv.x), f2=bflo(qv.y), f3=bfhi(qv.y);
    float f4=bflo(qv.z), f5=bfhi(qv.z), f6=bflo(qv.w), f7=bfhi(qv.w);
    // qn computed from the lambda-scaled Qu values -> lambda-scaled max bound (exact algebra)
    qn[t] = sqrtf(f0*f0+f1*f1+f2*f2+f3*f3+f4*f4+f5*f5+f6*f6+f7*f7)*1.01f + 1e-6f;
    #pragma unroll
    for (int rr=0; rr<3; rr++){
      const int gkb = ((k + NCHUNK-1 + rr) & (NCHUNK-1)) * CHU;
      int pk = spos[h*LTOT + gkb + t];
      *(uint4*)(Klds + (rr*CHU + t)*8) = *(const uint4*)(Ku + (size_t)pk*8);
    }
  }
  for (int j = t; j < 432; j += 320){
    int p = j >> 1, hf = j & 1;
    int g = 2*p;
    int rg = g / CHU, lk = g - rg*CHU;
    const int gkb = ((k + NCHUNK-1 + rg) & (NCHUNK-1)) * CHU;
    // lk is even -> 8B-aligned paired load of adjacent spos entries
    int2 pp = *(const int2*)(spos + h*LTOT + gkb + lk);
    int posA = pp.x, posB = pp.y;
    const uint4* ra = (const uint4*)(Vu + (size_t)posA*32);
    const uint4* rb = (const uint4*)(Vu + (size_t)posB*32);
    uint4 A0 = ra[hf*2], A1 = ra[hf*2+1];
    uint4 B0 = rb[hf*2], B1 = rb[hf*2+1];
    u32 aw[8] = {A0.x,A0.y,A0.z,A0.w,A1.x,A1.y,A1.z,A1.w};
    u32 bw[8] = {B0.x,B0.y,B0.z,B0.w,B1.x,B1.y,B1.z,B1.w};
    int ebase = hf*16;
    u16* vtb = (u16*)VT[rg];
    #pragma unroll
    for (int m=0;m<8;m++){
      u32 al = aw[m]&0xffffu, ah = aw[m]>>16;
      u32 bl = bw[m]&0xffffu, bh = bw[m]>>16;
      *(u32*)&vtb[(ebase+2*m  )*VTS + lk] = al | (bl<<16);
      *(u32*)&vtb[(ebase+2*m+1)*VTS + lk] = ah | (bh<<16);
    }
  }
  __syncthreads();

  const int lane = t & 63;
  const int wv = t >> 6;                 // 0..4
  const int q = lane & 15;
  const int quad = lane >> 4;
  const bool two = (wv < 4);
  const int tl0 = 2*wv;
  const int tl1 = two ? (2*wv+1) : 8;

  const short4v zs = {0,0,0,0};
  short4v bq0 = zs, bq1 = zs;
  if (quad < 2){
    bq0 = *(const short4v*)(Qlds + (tl0*16+q)*8 + quad*4);
    if (two) bq1 = *(const short4v*)(Qlds + (tl1*16+q)*8 + quad*4);
  }
  const float m0 = qn[tl0*16+q];
  const float m1 = two ? qn[tl1*16+q] : 0.f;
  const f32x4 cA0 = {-m0,-m0,-m0,-m0};   // -m folded into QK^T accumulator init
  const f32x4 cB0 = {-m1,-m1,-m1,-m1};

  f32x4 o00={0,0,0,0}, o01={0,0,0,0}, o10={0,0,0,0}, o11={0,0,0,0};
  float s0 = 0.f, s1 = 0.f;

  #pragma unroll 3
  for (int kt=0; kt<27; kt++){
    const int rg = kt / 9, ktl = kt - rg*9;
    const u16* vtb = VT[rg];
    short4v av = zs;
    if (quad < 2) av = *(const short4v*)(Klds + (kt*16+q)*8 + quad*4);
    f32x4 stA = __builtin_amdgcn_mfma_f32_16x16x16bf16_1k(av, bq0, cA0, 0,0,0);

    float pA0 = EXP2(stA[0]), pA1 = EXP2(stA[1]);
    float pA2 = EXP2(stA[2]), pA3 = EXP2(stA[3]);
    s0 += (pA0+pA1)+(pA2+pA3);
    union { u32 u[2]; short4v s4; } pkA;
    pkA.u[0] = pkbf(pA0,pA1); pkA.u[1] = pkbf(pA2,pA3);

    short4v va0 = *(const short4v*)(&vtb[ q    *VTS + ktl*16 + quad*4]);
    short4v va1 = *(const short4v*)(&vtb[(q+16)*VTS + ktl*16 + quad*4]);
    o00 = __builtin_amdgcn_mfma_f32_16x16x16bf16_1k(va0, pkA.s4, o00, 0,0,0);
    o01 = __builtin_amdgcn_mfma_f32_16x16x16bf16_1k(va1, pkA.s4, o01, 0,0,0);

    if (two){
      f32x4 stB = __builtin_amdgcn_mfma_f32_16x16x16bf16_1k(av, bq1, cB0, 0,0,0);
      float pB0 = EXP2(stB[0]), pB1 = EXP2(stB[1]);
      float pB2 = EXP2(stB[2]), pB3 = EXP2(stB[3]);
      s1 += (pB0+pB1)+(pB2+pB3);
      union { u32 u[2]; short4v s4; } pkB;
      pkB.u[0] = pkbf(pB0,pB1); pkB.u[1] = pkbf(pB2,pB3);
      o10 = __builtin_amdgcn_mfma_f32_16x16x16bf16_1k(va0, pkB.s4, o10, 0,0,0);
      o11 = __builtin_amdgcn_mfma_f32_16x16x16bf16_1k(va1, pkB.s4, o11, 0,0,0);
    }
  }

  float st0 = s0;
  st0 += __shfl_xor(st0, 16); st0 += __shfl_xor(st0, 32);
  float inv0 = 1.0f/st0;

  const int pos0 = spos_l[tl0*16 + q];
  u16* rp0 = ret_u + (size_t)(h*LTOT + pos0)*32;
  uint2 wA, wB;
  wA.x = pkbf(o00[0]*inv0, o00[1]*inv0); wA.y = pkbf(o00[2]*inv0, o00[3]*inv0);
  wB.x = pkbf(o01[0]*inv0, o01[1]*inv0); wB.y = pkbf(o01[2]*inv0, o01[3]*inv0);
  *(uint2*)&rp0[quad*4]    = wA;
  *(uint2*)&rp0[16+quad*4] = wB;
  if (quad == 0) bs_u[h*LTOT + pos0] = m0 + LOG2(st0);   // log2-domain bucket score (= lambda * ln-domain)

  if (two){
    float st1 = s1;
    st1 += __shfl_xor(st1, 16); st1 += __shfl_xor(st1, 32);
    float inv1 = 1.0f/st1;
    const int pos1 = spos_l[tl1*16 + q];
    u16* rp1 = ret_u + (size_t)(h*LTOT + pos1)*32;
    wA.x = pkbf(o10[0]*inv1, o10[1]*inv1); wA.y = pkbf(o10[2]*inv1, o10[3]*inv1);
    wB.x = pkbf(o11[0]*inv1, o11[1]*inv1); wB.y = pkbf(o11[2]*inv1, o11[3]*inv1);
    *(uint2*)&rp1[quad*4]    = wA;
    *(uint2*)&rp1[16+quad*4] = wB;
    if (quad == 0) bs_u[h*LTOT + pos1] = m1 + LOG2(st1);
  }
}

// ---------------- cross-hash softmax + residual — exp2-domain (exact: 2^(lambda*d) = e^d) ----------------
__global__ __launch_bounds__(256) void k_final(const float* __restrict__ x,
    const u16* __restrict__ ret_u, const float* __restrict__ bs_u,
    float* __restrict__ out)
{
  const int l  = blockIdx.x*64 + (threadIdx.x & 63);
  const int eg = threadIdx.x >> 6;
  float bs[NH];
  #pragma unroll
  for (int h=0;h<NH;h++) bs[h] = bs_u[h*LTOT + l];
  float m = fmaxf(fmaxf(bs[0],bs[1]), fmaxf(bs[2],bs[3]));
  float p[NH]; float s = 0.f;
  #pragma unroll
  for (int h=0;h<NH;h++){ p[h] = EXP2(bs[h]-m); s += p[h]; }
  float inv = 1.0f/s;
  float o[8];
  #pragma unroll
  for (int e=0;e<8;e++) o[e]=0.f;
  #pragma unroll
  for (int h=0;h<NH;h++){
    float w = p[h]*inv;
    uint4 v = *(const uint4*)(ret_u + (size_t)(h*LTOT + l)*32 + eg*8);
    o[0] += w*bflo(v.x); o[1] += w*bfhi(v.x);
    o[2] += w*bflo(v.y); o[3] += w*bfhi(v.y);
    o[4] += w*bflo(v.z); o[5] += w*bfhi(v.z);
    o[6] += w*bflo(v.w); o[7] += w*bfhi(v.w);
  }
  #pragma unroll
  for (int e=0;e<8;e++){
    int ge = eg*8 + e;
    out[ge*LTOT + l] = o[e] + x[ge*LTOT + l];
  }
}

extern "C" void kernel_launch(void* const* d_in, const int* in_sizes, int n_in,
                              void* d_out, int out_size, void* d_ws, size_t ws_size,
                              hipStream_t stream)
{
  const float* x   = (const float*)d_in[0];
  const float* wm  = (const float*)d_in[1];
  const float* bm  = (const float*)d_in[2];
  const float* wa  = (const float*)d_in[3];
  const float* ba  = (const float*)d_in[4];
  const float* rot = (const float*)d_in[5];
  float* out = (float*)d_out;

  char* ws = (char*)d_ws;
  size_t off = 0;
  auto alloc = [&](size_t bytes)->void*{
    void* p = ws + off;
    off = (off + bytes + 255) & ~(size_t)255;
    return p;
  };
  u16*   Ku     = (u16*)  alloc((size_t)LTOT*8*2);
  u16*   Qu     = (u16*)  alloc((size_t)LTOT*8*2);
  u16*   Vu     = (u16*)  alloc((size_t)LTOT*32*2);
  int*   code   = (int*)  alloc((size_t)NH*LTOT*4);
  int*   hist   = (int*)  alloc((size_t)NH*NSEG*NBUCK*4);
  int*   spos   = (int*)  alloc((size_t)NH*LTOT*4);
  u16*   ret_u  = (u16*)  alloc((size_t)NH*LTOT*32*2);
  float* bs_u   = (float*)alloc((size_t)NH*LTOT*4);

  hipMemsetAsync(hist, 0, (size_t)NH*NSEG*NBUCK*4, stream);
  hipLaunchKernelGGL(k_conv,   dim3(576),        dim3(256), 0, stream, x, wm, bm, wa, ba, rot, Ku, Qu, Vu, code, hist);
  hipLaunchKernelGGL(k_spos,   dim3(NSEG,NH),    dim3(256), 0, stream, code, hist, spos);
  hipLaunchKernelGGL(k_attn,   dim3(NCHUNK,NH),  dim3(320), 0, stream, Ku, Qu, Vu, spos, ret_u, bs_u);
  hipLaunchKernelGGL(k_final,  dim3(576),        dim3(256), 0, stream, x, ret_u, bs_u, out);
}